// Round 3
// baseline (8456.867 us; speedup 1.0000x reference)
//
#include <hip/hip_runtime.h>
#include <hip/hip_bf16.h>

__device__ __forceinline__ float eluf(float x){ return x > 0.f ? x : expm1f(x); }

// ---------------- generic 3x3 pad-1 conv ----------------
// out[((b*Ctot + ooff + o)*H + y)*W + x]; act: 0=none, 1=sigmoid
__global__ void conv3x3_kernel(const float* __restrict__ in, const float* __restrict__ w,
                               const float* __restrict__ bias, float* __restrict__ out,
                               int B, int Cin, int Cout, int H, int W, int Ctot, int ooff, int act)
{
  int idx = blockIdx.x*256 + threadIdx.x;
  int total = B*Cout*H*W;
  if (idx >= total) return;
  int x = idx % W; int t = idx / W;
  int y = t % H;   t /= H;
  int o = t % Cout; int b = t / Cout;
  float acc = bias ? bias[o] : 0.f;
  const float* wp = w + (long long)o*Cin*9;
  for (int c = 0; c < Cin; c++){
    const float* ip = in + (long long)(b*Cin + c)*H*W;
    const float* wc = wp + c*9;
    #pragma unroll
    for (int ky = 0; ky < 3; ky++){
      int iy = y + ky - 1; if ((unsigned)iy >= (unsigned)H) continue;
      #pragma unroll
      for (int kx = 0; kx < 3; kx++){
        int ix = x + kx - 1; if ((unsigned)ix >= (unsigned)W) continue;
        acc += wc[ky*3+kx] * ip[iy*W + ix];
      }
    }
  }
  if (act == 1) acc = 1.f/(1.f + expf(-acc));
  out[(((long long)b*Ctot + ooff + o)*H + y)*W + x] = acc;
}

// ---------------- per-channel sum / sumsq over (B,H,W) ----------------
__global__ void stats_kernel(const float* __restrict__ xin, float* __restrict__ sum,
                             float* __restrict__ sq, int C, int HW)
{
  __shared__ float s1[256], s2[256];
  int c = blockIdx.x % C;
  const float* p = xin + (long long)blockIdx.x*HW;
  float a = 0.f, b = 0.f;
  for (int i = threadIdx.x; i < HW; i += 256){ float v = p[i]; a += v; b += v*v; }
  s1[threadIdx.x] = a; s2[threadIdx.x] = b;
  __syncthreads();
  for (int st = 128; st > 0; st >>= 1){
    if (threadIdx.x < st){ s1[threadIdx.x] += s1[threadIdx.x+st]; s2[threadIdx.x] += s2[threadIdx.x+st]; }
    __syncthreads();
  }
  if (threadIdx.x == 0){ atomicAdd(&sum[c], s1[0]); atomicAdd(&sq[c], s2[0]); }
}

// ---------------- bn + elu + 2x2 avgpool ----------------
__global__ void bn_elu_pool_kernel(const float* __restrict__ in, const float* __restrict__ g,
                                   const float* __restrict__ bb, const float* __restrict__ sum,
                                   const float* __restrict__ sq, float* __restrict__ out,
                                   int B, int C, int H, int W, float invN)
{
  int Ho = H/2, Wo = W/2;
  int idx = blockIdx.x*256 + threadIdx.x;
  int total = B*C*Ho*Wo;
  if (idx >= total) return;
  int x = idx % Wo; int t = idx / Wo;
  int y = t % Ho;   t /= Ho;
  int c = t % C;    int b = t / C;
  float mean = sum[c]*invN;
  float var  = sq[c]*invN - mean*mean;
  float sc = g[c] * rsqrtf(var + 1e-5f);
  float sh = bb[c] - mean*sc;
  const float* p = in + (long long)(b*C + c)*H*W;
  float acc = 0.f;
  #pragma unroll
  for (int dy = 0; dy < 2; dy++)
    #pragma unroll
    for (int dx = 0; dx < 2; dx++)
      acc += eluf(sc*p[(2*y+dy)*W + (2*x+dx)] + sh);
  out[idx] = acc * 0.25f;
}

// ---------------- bn + elu in place ----------------
__global__ void bn_elu_inplace_kernel(float* __restrict__ xio, const float* __restrict__ g,
                                      const float* __restrict__ bb, const float* __restrict__ sum,
                                      const float* __restrict__ sq, int C, int HW, float invN, int total)
{
  int idx = blockIdx.x*256 + threadIdx.x;
  if (idx >= total) return;
  int c = (idx / HW) % C;
  float mean = sum[c]*invN;
  float var  = sq[c]*invN - mean*mean;
  float sc = g[c] * rsqrtf(var + 1e-5f);
  float sh = bb[c] - mean*sc;
  xio[idx] = eluf(sc*xio[idx] + sh);
}

// ---------------- fused deformable conv (sampling + 3x3-stride-3 conv) ----------------
// block = one (b,i,j); blockDim.x == Cout. om layout: 27 channels (0-8 off-x, 9-17 off-y, 18-26 mask)
__global__ void deform_kernel(const float* __restrict__ x, const float* __restrict__ om,
                              const float* __restrict__ w, float* __restrict__ out,
                              int B, int Cin, int Cout, int H, int W)
{
  __shared__ float s[1152];
  __shared__ float kw[9][4];
  __shared__ int   ki[9][4];
  __shared__ float km[9];
  int blk = blockIdx.x;
  int j = blk % W; int tt = blk / W;
  int i = tt % H;  int b  = tt / H;
  int t = threadIdx.x;
  int Hp = H + 2, Wp = W + 2;
  if (t < 9){
    int k = t;
    long long base = ((long long)b*27)*H*W + (long long)i*W + j;
    float offx = om[base + (long long)k*H*W];
    float offy = om[base + (long long)(9+k)*H*W];
    float mk   = om[base + (long long)(18+k)*H*W];   // already sigmoid'ed
    float pnx = (float)(k/3) - 1.f;
    float pny = (float)(k%3) - 1.f;
    float px = fminf(fmaxf((float)(i+1) + pnx + offx, 0.f), (float)(Hp-1));
    float py = fminf(fmaxf((float)(j+1) + pny + offy, 0.f), (float)(Wp-1));
    float fx = floorf(px), fy = floorf(py);
    float x0 = fmaxf(fx, 0.f), y0 = fmaxf(fy, 0.f);
    float x1c = fminf(fx + 1.f, (float)(Hp-1));
    float y1c = fminf(fy + 1.f, (float)(Wp-1));
    kw[k][0] = (1.f + (x0 - px)) * (1.f + (y0 - py));   // lt
    kw[k][1] = (1.f - (x1c - px)) * (1.f - (y1c - py)); // rb
    kw[k][2] = (1.f + (x0 - px)) * (1.f - (y1c - py)); // lb
    kw[k][3] = (1.f - (x1c - px)) * (1.f + (y0 - py)); // rt
    ki[k][0] = (int)x0; ki[k][1] = (int)y0; ki[k][2] = (int)x1c; ki[k][3] = (int)y1c;
    km[k] = mk;
  }
  __syncthreads();
  int total = Cin*9;
  for (int idx = t; idx < total; idx += blockDim.x){
    int c = idx / 9, k = idx % 9;
    const float* xp = x + (long long)(b*Cin + c)*H*W;
    float vlt, vrb, vlb, vrt;
    { int qx = ki[k][0], qy = ki[k][1];
      vlt = (qx >= 1 && qx <= H && qy >= 1 && qy <= W) ? xp[(qx-1)*W + (qy-1)] : 0.f; }
    { int qx = ki[k][2], qy = ki[k][3];
      vrb = (qx >= 1 && qx <= H && qy >= 1 && qy <= W) ? xp[(qx-1)*W + (qy-1)] : 0.f; }
    { int qx = ki[k][0], qy = ki[k][3];
      vlb = (qx >= 1 && qx <= H && qy >= 1 && qy <= W) ? xp[(qx-1)*W + (qy-1)] : 0.f; }
    { int qx = ki[k][2], qy = ki[k][1];
      vrt = (qx >= 1 && qx <= H && qy >= 1 && qy <= W) ? xp[(qx-1)*W + (qy-1)] : 0.f; }
    float v = kw[k][0]*vlt + kw[k][1]*vrb + kw[k][2]*vlb + kw[k][3]*vrt;
    s[idx] = v * km[k];
  }
  __syncthreads();
  if (t < Cout){
    const float* wr = w + (long long)t*total;
    float acc = 0.f;
    for (int q = 0; q < total; q++) acc += wr[q] * s[q];
    out[(((long long)b*Cout + t)*H + i)*W + j] = acc;
  }
}

// ---------------- generic transpose conv ----------------
// weight layout (Cin, Cout, K, K)
__global__ void convt_kernel(const float* __restrict__ in, const float* __restrict__ w,
                             const float* __restrict__ bias, float* __restrict__ out,
                             int B, int Cin, int Cout, int Hin, int Win, int Hout, int Wout,
                             int K, int S, int PP, int do_elu)
{
  int idx = blockIdx.x*256 + threadIdx.x;
  int total = B*Cout*Hout*Wout;
  if (idx >= total) return;
  int x = idx % Wout; int t = idx / Wout;
  int y = t % Hout;   t /= Hout;
  int o = t % Cout;   int b = t / Cout;
  float acc = bias[o];
  for (int ky = 0; ky < K; ky++){
    int dy = y + ky - PP;
    if (dy < 0 || (dy % S) != 0) continue;
    int iy = dy / S; if (iy >= Hin) continue;
    int wky = K - 1 - ky;
    for (int kx = 0; kx < K; kx++){
      int dx = x + kx - PP;
      if (dx < 0 || (dx % S) != 0) continue;
      int ix = dx / S; if (ix >= Win) continue;
      int wkx = K - 1 - kx;
      const float* ip = in + (long long)b*Cin*Hin*Win + (long long)iy*Win + ix;
      for (int c = 0; c < Cin; c++){
        acc += w[(((long long)c*Cout + o)*K + wky)*K + wkx] * ip[(long long)c*Hin*Win];
      }
    }
  }
  if (do_elu) acc = eluf(acc);
  out[idx] = acc;
}

// ---------------- final bicubic warp ----------------
__device__ __forceinline__ float cubicf(float A, float Bv, float C, float D, float t){
  float a = -0.5f*A + 1.5f*Bv - 1.5f*C + 0.5f*D;
  float b =  A - 2.5f*Bv + 2.0f*C - 0.5f*D;
  float c = -0.5f*A + 0.5f*C;
  return ((a*t + b)*t + c)*t + Bv;
}

__global__ void warp_kernel(const float* __restrict__ V /* t1m: (B,2,28,28) */,
                            const float* __restrict__ x1, float* __restrict__ out, int B)
{
  int idx = blockIdx.x*256 + threadIdx.x;
  int total = B*784;
  if (idx >= total) return;
  int j = idx % 28; int t = idx / 28;
  int i = t % 28;   int b = t / 28;
  // Vt = t1m.transpose(0,3,2,1): V[b,i,j,ch] = t1m[b,ch,j,i]
  float v0 = V[((long long)b*2 + 0)*784 + j*28 + i];
  float v1 = V[((long long)b*2 + 1)*784 + j*28 + i];
  float gx = (-1.f + 2.f*(float)j/27.f) + v0;
  float gy = (-1.f + 2.f*(float)i/27.f) + v1;
  float ix = (gx + 1.f)*13.5f;
  float iy = (gy + 1.f)*13.5f;
  float x0 = floorf(ix), y0 = floorf(iy);
  float tx = ix - x0, ty = iy - y0;
  const float* img = x1 + (long long)b*2*784;  // channel 0 of x1
  float rows[4];
  #pragma unroll
  for (int ky = -1; ky <= 2; ky++){
    int yi = (int)fminf(fmaxf(y0 + (float)ky, 0.f), 27.f);
    float cv[4];
    #pragma unroll
    for (int kx = -1; kx <= 2; kx++){
      int xi = (int)fminf(fmaxf(x0 + (float)kx, 0.f), 27.f);
      cv[kx+1] = img[yi*28 + xi];
    }
    rows[ky+1] = cubicf(cv[0], cv[1], cv[2], cv[3], tx);
  }
  out[idx] = cubicf(rows[0], rows[1], rows[2], rows[3], ty);
}

// ---------------- host ----------------
extern "C" void kernel_launch(void* const* d_in, const int* in_sizes, int n_in,
                              void* d_out, int out_size, void* d_ws, size_t ws_size,
                              hipStream_t stream)
{
  const int B = 256;
  const float* x1      = (const float*)d_in[0];
  const float* conv1_w = (const float*)d_in[9];
  const float* conv1_b = (const float*)d_in[10];
  const float* bn1_g   = (const float*)d_in[11];
  const float* bn1_b   = (const float*)d_in[12];
  const float* dc2_pw  = (const float*)d_in[13];
  const float* dc2_pb  = (const float*)d_in[14];
  const float* dc2_mw  = (const float*)d_in[15];
  const float* dc2_mb  = (const float*)d_in[16];
  const float* dc2_w   = (const float*)d_in[17];
  const float* bn2_g   = (const float*)d_in[18];
  const float* bn2_b   = (const float*)d_in[19];
  const float* conv3_w = (const float*)d_in[20];
  const float* conv3_b = (const float*)d_in[21];
  const float* bn3_g   = (const float*)d_in[22];
  const float* bn3_b   = (const float*)d_in[23];
  const float* dc41_pw = (const float*)d_in[24];
  const float* dc41_pb = (const float*)d_in[25];
  const float* dc41_mw = (const float*)d_in[26];
  const float* dc41_mb = (const float*)d_in[27];
  const float* dc41_w  = (const float*)d_in[28];
  const float* bn41_g  = (const float*)d_in[29];
  const float* bn41_b  = (const float*)d_in[30];
  const float* conv4_w = (const float*)d_in[31];
  const float* conv4_b = (const float*)d_in[32];
  const float* conv4m_w= (const float*)d_in[33];
  const float* conv4m_b= (const float*)d_in[34];
  const float* conv3m_w= (const float*)d_in[35];
  const float* conv3m_b= (const float*)d_in[36];
  const float* conv2m_w= (const float*)d_in[37];
  const float* conv2m_b= (const float*)d_in[38];
  const float* conv1m_w= (const float*)d_in[39];
  const float* conv1m_b= (const float*)d_in[40];

  float* ws = (float*)d_ws;

  // ---- lifetime-packed arena (floats). Peak ≈ 18.9M floats ≈ 75.5 MB ----
  // stats live in [0,1024)
  const long long AB = 1024;
  float* p1   = ws + AB;               // 3,211,264   live [2..4]
  float* a1   = ws + AB + 3211264;     // 12,845,056  live [1..2]
  float* om2  = ws + AB + 3211264;     // 1,354,752   live [3..4]  (a1 dead)
  float* a2   = ws + AB + 4566016;     // 6,422,528   live [4..6]
  float* a3   = ws + AB + 10988544;    // 6,422,528   live [6..7]
  float* p2   = ws + AB;               // 1,605,632   live [7..9]  (p1 dead)
  float* om41 = ws + AB + 1605632;     //   338,688   live [8..9]
  float* a41  = ws + AB + 1944320;     //   802,816   live [9..11]
  float* a4   = ws + AB + 2747136;     //    25,088   live [11..12]
  float* t4m  = ws + AB + 2772224;     // 5,537,792   live [12..13]
  float* t3m  = ws + AB + 8310016;     // 3,686,400   live [13..14] (a3 dead)
  float* t2m  = ws + AB + 11996416;    // 6,889,472   live [14..15]
  float* t1m  = ws + AB;               //   401,408   live [15..16] (p2 dead)

  // bn stats sum/sq pairs inside [0,1024)
  float* s1  = ws + 0;   float* q1  = ws + 64;
  float* s2  = ws + 128; float* q2  = ws + 256;
  float* s3  = ws + 384; float* q3  = ws + 512;
  float* s41 = ws + 640; float* q41 = ws + 704;

  auto nb = [](long long n){ return (int)((n + 255)/256); };

  // zero the stats region (ws is poisoned 0xAA before each timed call)
  hipMemsetAsync(d_ws, 0, 4096, stream);

  // [1] conv1 (2->64, 28x28, pad1) -> a1
  conv3x3_kernel<<<nb((long long)B*64*784), 256, 0, stream>>>(x1, conv1_w, conv1_b, a1,
                                                              B, 2, 64, 28, 28, 64, 0, 0);
  // [2] bn1 stats, bn+elu+avgpool -> p1 (64,14,14)
  stats_kernel<<<B*64, 256, 0, stream>>>(a1, s1, q1, 64, 784);
  bn_elu_pool_kernel<<<nb((long long)B*64*196), 256, 0, stream>>>(a1, bn1_g, bn1_b, s1, q1, p1,
                                                                  B, 64, 28, 28, 1.f/200704.f);
  // [3] dc2 offsets (64->18) and mask (64->9, sigmoid) -> om2 (27 ch)
  conv3x3_kernel<<<nb((long long)B*18*196), 256, 0, stream>>>(p1, dc2_pw, dc2_pb, om2,
                                                              B, 64, 18, 14, 14, 27, 0, 0);
  conv3x3_kernel<<<nb((long long)B*9*196), 256, 0, stream>>>(p1, dc2_mw, dc2_mb, om2,
                                                             B, 64, 9, 14, 14, 27, 18, 1);
  // [4] fused deform conv 2 (64 -> 128) -> a2
  deform_kernel<<<B*196, 128, 0, stream>>>(p1, om2, dc2_w, a2, B, 64, 128, 14, 14);
  // [5] bn2 + elu (in place)
  stats_kernel<<<B*128, 256, 0, stream>>>(a2, s2, q2, 128, 196);
  bn_elu_inplace_kernel<<<nb((long long)B*128*196), 256, 0, stream>>>(a2, bn2_g, bn2_b, s2, q2,
                                                                      128, 196, 1.f/50176.f, B*128*196);
  // [6] conv3 (128->128, 14x14) -> a3
  conv3x3_kernel<<<nb((long long)B*128*196), 256, 0, stream>>>(a2, conv3_w, conv3_b, a3,
                                                               B, 128, 128, 14, 14, 128, 0, 0);
  // [7] bn3 stats, bn+elu+avgpool -> p2 (128,7,7)
  stats_kernel<<<B*128, 256, 0, stream>>>(a3, s3, q3, 128, 196);
  bn_elu_pool_kernel<<<nb((long long)B*128*49), 256, 0, stream>>>(a3, bn3_g, bn3_b, s3, q3, p2,
                                                                  B, 128, 14, 14, 1.f/50176.f);
  // [8] dc41 offsets/mask -> om41
  conv3x3_kernel<<<nb((long long)B*18*49), 256, 0, stream>>>(p2, dc41_pw, dc41_pb, om41,
                                                             B, 128, 18, 7, 7, 27, 0, 0);
  conv3x3_kernel<<<nb((long long)B*9*49), 256, 0, stream>>>(p2, dc41_mw, dc41_mb, om41,
                                                            B, 128, 9, 7, 7, 27, 18, 1);
  // [9] fused deform conv 41 (128 -> 64) -> a41
  deform_kernel<<<B*49, 64, 0, stream>>>(p2, om41, dc41_w, a41, B, 128, 64, 7, 7);
  // [10] bn41 + elu (in place)
  stats_kernel<<<B*64, 256, 0, stream>>>(a41, s41, q41, 64, 49);
  bn_elu_inplace_kernel<<<nb((long long)B*64*49), 256, 0, stream>>>(a41, bn41_g, bn41_b, s41, q41,
                                                                    64, 49, 1.f/12544.f, B*64*49);
  // [11] conv4 (64->2, 7x7, pad1) -> a4
  conv3x3_kernel<<<nb((long long)B*2*49), 256, 0, stream>>>(a41, conv4_w, conv4_b, a4,
                                                            B, 64, 2, 7, 7, 2, 0, 0);
  // (bicubic 7->7 is identity)
  // [12] convT4m: 2->128, s=2, p=1, 7->13
  convt_kernel<<<nb((long long)B*128*169), 256, 0, stream>>>(a4, conv4m_w, conv4m_b, t4m,
                                                             B, 2, 128, 7, 7, 13, 13, 3, 2, 1, 0);
  // [13] convT3m: 128->64, s=1, p=0, 13->15, +elu
  convt_kernel<<<nb((long long)B*64*225), 256, 0, stream>>>(t4m, conv3m_w, conv3m_b, t3m,
                                                            B, 128, 64, 13, 13, 15, 15, 3, 1, 2, 1);
  // [14] convT2m: 64->32, s=2, p=1, 15->29, +elu
  convt_kernel<<<nb((long long)B*32*841), 256, 0, stream>>>(t3m, conv2m_w, conv2m_b, t2m,
                                                            B, 64, 32, 15, 15, 29, 29, 3, 2, 1, 1);
  // [15] convT1m: 32->2, k=2, s=1, p=1, 29->28, +elu
  convt_kernel<<<nb((long long)B*2*784), 256, 0, stream>>>(t2m, conv1m_w, conv1m_b, t1m,
                                                           B, 32, 2, 29, 29, 28, 28, 2, 1, 0, 1);
  // (bicubic 28->28 is identity) [16] final warp
  warp_kernel<<<nb((long long)B*784), 256, 0, stream>>>(t1m, x1, (float*)d_out, B);
}

// Round 4
// 3204.380 us; speedup vs baseline: 2.6392x; 2.6392x over previous
//
#include <hip/hip_runtime.h>
#include <hip/hip_bf16.h>

__device__ __forceinline__ float eluf(float x){ return x > 0.f ? x : expm1f(x); }

// ---------------- naive 3x3 pad-1 conv (kept for conv1 (H=28) and tiny conv4) ----------------
__global__ void conv3x3_kernel(const float* __restrict__ in, const float* __restrict__ w,
                               const float* __restrict__ bias, float* __restrict__ out,
                               int B, int Cin, int Cout, int H, int W, int Ctot, int ooff, int act)
{
  int idx = blockIdx.x*256 + threadIdx.x;
  int total = B*Cout*H*W;
  if (idx >= total) return;
  int x = idx % W; int t = idx / W;
  int y = t % H;   t /= H;
  int o = t % Cout; int b = t / Cout;
  float acc = bias ? bias[o] : 0.f;
  const float* wp = w + (long long)o*Cin*9;
  for (int c = 0; c < Cin; c++){
    const float* ip = in + (long long)(b*Cin + c)*H*W;
    const float* wc = wp + c*9;
    #pragma unroll
    for (int ky = 0; ky < 3; ky++){
      int iy = y + ky - 1; if ((unsigned)iy >= (unsigned)H) continue;
      #pragma unroll
      for (int kx = 0; kx < 3; kx++){
        int ix = x + kx - 1; if ((unsigned)ix >= (unsigned)W) continue;
        acc += wc[ky*3+kx] * ip[iy*W + ix];
      }
    }
  }
  if (act == 1) acc = 1.f/(1.f + expf(-acc));
  out[(((long long)b*Ctot + ooff + o)*H + y)*W + x] = acc;
}

// ---------------- tiled 3x3 conv: block=(b, 16-o tile), 256 thr = 16o x 16y ----------------
// TRANSP: weight layout (Cin, CoutW, 3,3) read flipped (transpose-conv as conv)
// act: 0 none, 1 sigmoid, 2 elu
template<int HIN,int WIN,int HOUT,int WOUT,int PAD,bool TRANSP>
__global__ __launch_bounds__(256)
void conv_tiled(const float* __restrict__ in, const float* __restrict__ w,
                const float* __restrict__ bias, float* __restrict__ out,
                int Cin, int Cout, int CoutW, int Ctot, int ooff, int act)
{
  constexpr int HP = HIN + 2*PAD, WP = WIN + 2*PAD, WPL = WP + 1;
  __shared__ float img[HP*WPL];
  __shared__ float wl[16*9];
  const int b  = blockIdx.x;
  const int o0 = blockIdx.y * 16;
  const int t  = threadIdx.x;
  const int ol = t >> 4, y = t & 15;
  const bool act_th = (y < HOUT) && (o0 + ol < Cout);
  float acc[WOUT];
  #pragma unroll
  for (int x = 0; x < WOUT; x++) acc[x] = 0.f;
  for (int idx = t; idx < HP*WPL; idx += 256) img[idx] = 0.f;  // zero borders
  const long long inb = (long long)b*Cin*HIN*WIN;
  for (int c = 0; c < Cin; c++){
    __syncthreads();
    for (int idx = t; idx < HIN*WIN; idx += 256){
      int iy = idx / WIN, ix = idx % WIN;
      img[(iy+PAD)*WPL + (ix+PAD)] = in[inb + (long long)c*HIN*WIN + idx];
    }
    if (t < 144){
      int oo = t / 9, kk = t % 9;
      int og = o0 + oo;
      float wv = 0.f;
      if (og < Cout){
        if (TRANSP) wv = w[((long long)c*CoutW + og)*9 + (2 - kk/3)*3 + (2 - kk%3)];
        else        wv = w[((long long)og*Cin + c)*9 + kk];
      }
      wl[t] = wv;
    }
    __syncthreads();
    if (act_th){
      #pragma unroll
      for (int ky = 0; ky < 3; ky++){
        const float* row = &img[(y+ky)*WPL];
        float rin[WOUT+2];
        #pragma unroll
        for (int x = 0; x < WOUT+2; x++) rin[x] = row[x];
        #pragma unroll
        for (int kx = 0; kx < 3; kx++){
          float wv = wl[ol*9 + ky*3 + kx];
          #pragma unroll
          for (int x = 0; x < WOUT; x++) acc[x] += wv * rin[x+kx];
        }
      }
    }
  }
  if (act_th){
    int og = o0 + ol;
    float bv = bias[og];
    #pragma unroll
    for (int x = 0; x < WOUT; x++){
      float v = acc[x] + bv;
      if (act == 1) v = 1.f/(1.f + expf(-v));
      else if (act == 2) v = eluf(v);
      out[(((long long)b*Ctot + ooff + og)*HOUT + y)*WOUT + x] = v;
    }
  }
}

// ---------------- deformable conv as fused gather-GEMM ----------------
// block=(b, px-tile). threads = COUT*PXG (<=256); wave lanes span o -> S reads broadcast.
template<int CIN,int COUT,int H,int W,int PXT,int PXG>
__global__ __launch_bounds__(256)
void deform_gemm(const float* __restrict__ x, const float* __restrict__ om,
                 const float* __restrict__ w, float* __restrict__ out)
{
  constexpr int HW = H*W;
  constexpr int NT = (HW + PXT - 1)/PXT;
  constexpr int PPT = (PXT + PXG - 1)/PXG;
  constexpr int PXTP = PPT*PXG;
  __shared__ float simg[8*HW];
  __shared__ float S[72*PXTP];
  __shared__ float kwv[PXT*9*4];
  __shared__ int   kidx[PXT*9*4];
  const int tile = blockIdx.x % NT;
  const int b    = blockIdx.x / NT;
  const int t    = threadIdx.x;
  const int o    = t % COUT;
  const int pxg  = t / COUT;
  const int Hp = H + 2, Wp = W + 2;
  // phase 0: per (px,kk) bilinear corner indices & weights (mask folded in)
  for (int it = t; it < PXT*9; it += 256){
    int px = it / 9, kk = it % 9;
    int p = tile*PXT + px;
    float w0=0.f,w1=0.f,w2=0.f,w3=0.f;
    int i0=0,i1=0,i2=0,i3=0;
    if (p < HW){
      int i = p / W, j = p % W;
      long long base = ((long long)b*27)*HW + p;
      float offx = om[base + (long long)kk*HW];
      float offy = om[base + (long long)(9+kk)*HW];
      float mk   = om[base + (long long)(18+kk)*HW];
      float pnx = (float)(kk/3) - 1.f;
      float pny = (float)(kk%3) - 1.f;
      float px_ = fminf(fmaxf((float)(i+1) + pnx + offx, 0.f), (float)(Hp-1));
      float py_ = fminf(fmaxf((float)(j+1) + pny + offy, 0.f), (float)(Wp-1));
      float fx = floorf(px_), fy = floorf(py_);
      float x0 = fmaxf(fx, 0.f), y0 = fmaxf(fy, 0.f);
      float x1c = fminf(fx + 1.f, (float)(Hp-1));
      float y1c = fminf(fy + 1.f, (float)(Wp-1));
      float glt = (1.f + (x0 - px_)) * (1.f + (y0 - py_));
      float grb = (1.f - (x1c - px_)) * (1.f - (y1c - py_));
      float glb = (1.f + (x0 - px_)) * (1.f - (y1c - py_));
      float grt = (1.f - (x1c - px_)) * (1.f + (y0 - py_));
      int ax0=(int)x0, ay0=(int)y0, ax1=(int)x1c, ay1=(int)y1c;
      // corner (qx,qy): valid iff inside unpadded [1,H]x[1,W]
      if (ax0>=1 && ax0<=H && ay0>=1 && ay0<=W){ w0 = glt*mk; i0 = (ax0-1)*W + (ay0-1); }
      if (ax1>=1 && ax1<=H && ay1>=1 && ay1<=W){ w1 = grb*mk; i1 = (ax1-1)*W + (ay1-1); }
      if (ax0>=1 && ax0<=H && ay1>=1 && ay1<=W){ w2 = glb*mk; i2 = (ax0-1)*W + (ay1-1); }
      if (ax1>=1 && ax1<=H && ay0>=1 && ay0<=W){ w3 = grt*mk; i3 = (ax1-1)*W + (ay0-1); }
    }
    int b4 = it*4;
    kwv[b4+0]=w0; kwv[b4+1]=w1; kwv[b4+2]=w2; kwv[b4+3]=w3;
    kidx[b4+0]=i0; kidx[b4+1]=i1; kidx[b4+2]=i2; kidx[b4+3]=i3;
  }
  float acc[PPT];
  #pragma unroll
  for (int pp = 0; pp < PPT; pp++) acc[pp] = 0.f;
  const float* wrow = w + (long long)o*CIN*9;
  for (int cc = 0; cc < CIN/8; cc++){
    __syncthreads();
    for (int idx = t; idx < 8*HW; idx += 256)
      simg[idx] = x[((long long)b*CIN + cc*8)*HW + idx];
    __syncthreads();
    for (int idx = t; idx < 72*PXT; idx += 256){
      int k = idx / PXT, px = idx % PXT;
      int cl = k / 9, kk = k % 9;
      int b4 = (px*9 + kk)*4;
      const float* im = &simg[cl*HW];
      float v = kwv[b4+0]*im[kidx[b4+0]] + kwv[b4+1]*im[kidx[b4+1]]
              + kwv[b4+2]*im[kidx[b4+2]] + kwv[b4+3]*im[kidx[b4+3]];
      S[k*PXTP + px] = v;
    }
    __syncthreads();
    const float* wc = wrow + cc*72;
    #pragma unroll 4
    for (int k = 0; k < 72; k++){
      float wv = wc[k];
      #pragma unroll
      for (int pp = 0; pp < PPT; pp++)
        acc[pp] += wv * S[k*PXTP + pxg*PPT + pp];
    }
  }
  #pragma unroll
  for (int pp = 0; pp < PPT; pp++){
    int pxl = pxg*PPT + pp;
    int p = tile*PXT + pxl;
    if (pxl < PXT && p < HW)
      out[((long long)b*COUT + o)*HW + p] = acc[pp];
  }
}

// ---------------- per-channel sum / sumsq ----------------
__global__ void stats_kernel(const float* __restrict__ xin, float* __restrict__ sum,
                             float* __restrict__ sq, int C, int HW)
{
  __shared__ float s1[256], s2[256];
  int c = blockIdx.x % C;
  const float* p = xin + (long long)blockIdx.x*HW;
  float a = 0.f, b = 0.f;
  for (int i = threadIdx.x; i < HW; i += 256){ float v = p[i]; a += v; b += v*v; }
  s1[threadIdx.x] = a; s2[threadIdx.x] = b;
  __syncthreads();
  for (int st = 128; st > 0; st >>= 1){
    if (threadIdx.x < st){ s1[threadIdx.x] += s1[threadIdx.x+st]; s2[threadIdx.x] += s2[threadIdx.x+st]; }
    __syncthreads();
  }
  if (threadIdx.x == 0){ atomicAdd(&sum[c], s1[0]); atomicAdd(&sq[c], s2[0]); }
}

// ---------------- bn + elu + 2x2 avgpool ----------------
__global__ void bn_elu_pool_kernel(const float* __restrict__ in, const float* __restrict__ g,
                                   const float* __restrict__ bb, const float* __restrict__ sum,
                                   const float* __restrict__ sq, float* __restrict__ out,
                                   int B, int C, int H, int W, float invN)
{
  int Ho = H/2, Wo = W/2;
  int idx = blockIdx.x*256 + threadIdx.x;
  int total = B*C*Ho*Wo;
  if (idx >= total) return;
  int x = idx % Wo; int t = idx / Wo;
  int y = t % Ho;   t /= Ho;
  int c = t % C;    int b = t / C;
  float mean = sum[c]*invN;
  float var  = sq[c]*invN - mean*mean;
  float sc = g[c] * rsqrtf(var + 1e-5f);
  float sh = bb[c] - mean*sc;
  const float* p = in + (long long)(b*C + c)*H*W;
  float acc = 0.f;
  #pragma unroll
  for (int dy = 0; dy < 2; dy++)
    #pragma unroll
    for (int dx = 0; dx < 2; dx++)
      acc += eluf(sc*p[(2*y+dy)*W + (2*x+dx)] + sh);
  out[idx] = acc * 0.25f;
}

// ---------------- bn + elu in place ----------------
__global__ void bn_elu_inplace_kernel(float* __restrict__ xio, const float* __restrict__ g,
                                      const float* __restrict__ bb, const float* __restrict__ sum,
                                      const float* __restrict__ sq, int C, int HW, float invN, int total)
{
  int idx = blockIdx.x*256 + threadIdx.x;
  if (idx >= total) return;
  int c = (idx / HW) % C;
  float mean = sum[c]*invN;
  float var  = sq[c]*invN - mean*mean;
  float sc = g[c] * rsqrtf(var + 1e-5f);
  float sh = bb[c] - mean*sc;
  xio[idx] = eluf(sc*xio[idx] + sh);
}

// ---------------- generic transpose conv (kept for convT4m/convT2m/convT1m) ----------------
__global__ void convt_kernel(const float* __restrict__ in, const float* __restrict__ w,
                             const float* __restrict__ bias, float* __restrict__ out,
                             int B, int Cin, int Cout, int Hin, int Win, int Hout, int Wout,
                             int K, int S, int PP, int do_elu)
{
  int idx = blockIdx.x*256 + threadIdx.x;
  int total = B*Cout*Hout*Wout;
  if (idx >= total) return;
  int x = idx % Wout; int t = idx / Wout;
  int y = t % Hout;   t /= Hout;
  int o = t % Cout;   int b = t / Cout;
  float acc = bias[o];
  for (int ky = 0; ky < K; ky++){
    int dy = y + ky - PP;
    if (dy < 0 || (dy % S) != 0) continue;
    int iy = dy / S; if (iy >= Hin) continue;
    int wky = K - 1 - ky;
    for (int kx = 0; kx < K; kx++){
      int dx = x + kx - PP;
      if (dx < 0 || (dx % S) != 0) continue;
      int ix = dx / S; if (ix >= Win) continue;
      int wkx = K - 1 - kx;
      const float* ip = in + (long long)b*Cin*Hin*Win + (long long)iy*Win + ix;
      for (int c = 0; c < Cin; c++){
        acc += w[(((long long)c*Cout + o)*K + wky)*K + wkx] * ip[(long long)c*Hin*Win];
      }
    }
  }
  if (do_elu) acc = eluf(acc);
  out[idx] = acc;
}

// ---------------- final bicubic warp ----------------
__device__ __forceinline__ float cubicf(float A, float Bv, float C, float D, float t){
  float a = -0.5f*A + 1.5f*Bv - 1.5f*C + 0.5f*D;
  float b =  A - 2.5f*Bv + 2.0f*C - 0.5f*D;
  float c = -0.5f*A + 0.5f*C;
  return ((a*t + b)*t + c)*t + Bv;
}

__global__ void warp_kernel(const float* __restrict__ V, const float* __restrict__ x1,
                            float* __restrict__ out, int B)
{
  int idx = blockIdx.x*256 + threadIdx.x;
  int total = B*784;
  if (idx >= total) return;
  int j = idx % 28; int t = idx / 28;
  int i = t % 28;   int b = t / 28;
  float v0 = V[((long long)b*2 + 0)*784 + j*28 + i];
  float v1 = V[((long long)b*2 + 1)*784 + j*28 + i];
  float gx = (-1.f + 2.f*(float)j/27.f) + v0;
  float gy = (-1.f + 2.f*(float)i/27.f) + v1;
  float ix = (gx + 1.f)*13.5f;
  float iy = (gy + 1.f)*13.5f;
  float x0 = floorf(ix), y0 = floorf(iy);
  float tx = ix - x0, ty = iy - y0;
  const float* img = x1 + (long long)b*2*784;
  float rows[4];
  #pragma unroll
  for (int ky = -1; ky <= 2; ky++){
    int yi = (int)fminf(fmaxf(y0 + (float)ky, 0.f), 27.f);
    float cv[4];
    #pragma unroll
    for (int kx = -1; kx <= 2; kx++){
      int xi = (int)fminf(fmaxf(x0 + (float)kx, 0.f), 27.f);
      cv[kx+1] = img[yi*28 + xi];
    }
    rows[ky+1] = cubicf(cv[0], cv[1], cv[2], cv[3], tx);
  }
  out[idx] = cubicf(rows[0], rows[1], rows[2], rows[3], ty);
}

// ---------------- host ----------------
extern "C" void kernel_launch(void* const* d_in, const int* in_sizes, int n_in,
                              void* d_out, int out_size, void* d_ws, size_t ws_size,
                              hipStream_t stream)
{
  const int B = 256;
  const float* x1      = (const float*)d_in[0];
  const float* conv1_w = (const float*)d_in[9];
  const float* conv1_b = (const float*)d_in[10];
  const float* bn1_g   = (const float*)d_in[11];
  const float* bn1_b   = (const float*)d_in[12];
  const float* dc2_pw  = (const float*)d_in[13];
  const float* dc2_pb  = (const float*)d_in[14];
  const float* dc2_mw  = (const float*)d_in[15];
  const float* dc2_mb  = (const float*)d_in[16];
  const float* dc2_w   = (const float*)d_in[17];
  const float* bn2_g   = (const float*)d_in[18];
  const float* bn2_b   = (const float*)d_in[19];
  const float* conv3_w = (const float*)d_in[20];
  const float* conv3_b = (const float*)d_in[21];
  const float* bn3_g   = (const float*)d_in[22];
  const float* bn3_b   = (const float*)d_in[23];
  const float* dc41_pw = (const float*)d_in[24];
  const float* dc41_pb = (const float*)d_in[25];
  const float* dc41_mw = (const float*)d_in[26];
  const float* dc41_mb = (const float*)d_in[27];
  const float* dc41_w  = (const float*)d_in[28];
  const float* bn41_g  = (const float*)d_in[29];
  const float* bn41_b  = (const float*)d_in[30];
  const float* conv4_w = (const float*)d_in[31];
  const float* conv4_b = (const float*)d_in[32];
  const float* conv4m_w= (const float*)d_in[33];
  const float* conv4m_b= (const float*)d_in[34];
  const float* conv3m_w= (const float*)d_in[35];
  const float* conv3m_b= (const float*)d_in[36];
  const float* conv2m_w= (const float*)d_in[37];
  const float* conv2m_b= (const float*)d_in[38];
  const float* conv1m_w= (const float*)d_in[39];
  const float* conv1m_b= (const float*)d_in[40];

  float* ws = (float*)d_ws;

  // lifetime-packed arena (floats), stats in [0,1024)
  const long long AB = 1024;
  float* p1   = ws + AB;               // live [2..4]
  float* a1   = ws + AB + 3211264;     // live [1..2]
  float* om2  = ws + AB + 3211264;     // live [3..4]
  float* a2   = ws + AB + 4566016;     // live [4..6]
  float* a3   = ws + AB + 10988544;    // live [6..7]
  float* p2   = ws + AB;               // live [7..9]
  float* om41 = ws + AB + 1605632;     // live [8..9]
  float* a41  = ws + AB + 1944320;     // live [9..11]
  float* a4   = ws + AB + 2747136;     // live [11..12]
  float* t4m  = ws + AB + 2772224;     // live [12..13]
  float* t3m  = ws + AB + 8310016;     // live [13..14]
  float* t2m  = ws + AB + 11996416;    // live [14..15]
  float* t1m  = ws + AB;               // live [15..16]

  float* s1  = ws + 0;   float* q1  = ws + 64;
  float* s2  = ws + 128; float* q2  = ws + 256;
  float* s3  = ws + 384; float* q3  = ws + 512;
  float* s41 = ws + 640; float* q41 = ws + 704;

  auto nb = [](long long n){ return (int)((n + 255)/256); };

  hipMemsetAsync(d_ws, 0, 4096, stream);

  // [1] conv1 (2->64, 28x28) naive
  conv3x3_kernel<<<nb((long long)B*64*784), 256, 0, stream>>>(x1, conv1_w, conv1_b, a1,
                                                              B, 2, 64, 28, 28, 64, 0, 0);
  // [2] bn1 + elu + avgpool -> p1
  stats_kernel<<<B*64, 256, 0, stream>>>(a1, s1, q1, 64, 784);
  bn_elu_pool_kernel<<<nb((long long)B*64*196), 256, 0, stream>>>(a1, bn1_g, bn1_b, s1, q1, p1,
                                                                  B, 64, 28, 28, 1.f/200704.f);
  // [3] dc2 offsets (64->18) + mask (64->9, sigmoid) -> om2
  conv_tiled<14,14,14,14,1,false><<<dim3(B,2), 256, 0, stream>>>(p1, dc2_pw, dc2_pb, om2,
                                                                 64, 18, 0, 27, 0, 0);
  conv_tiled<14,14,14,14,1,false><<<dim3(B,1), 256, 0, stream>>>(p1, dc2_mw, dc2_mb, om2,
                                                                 64, 9, 0, 27, 18, 1);
  // [4] deform conv 2 (64->128) -> a2
  deform_gemm<64,128,14,14,49,2><<<B*4, 256, 0, stream>>>(p1, om2, dc2_w, a2);
  // [5] bn2 + elu
  stats_kernel<<<B*128, 256, 0, stream>>>(a2, s2, q2, 128, 196);
  bn_elu_inplace_kernel<<<nb((long long)B*128*196), 256, 0, stream>>>(a2, bn2_g, bn2_b, s2, q2,
                                                                      128, 196, 1.f/50176.f, B*128*196);
  // [6] conv3 (128->128) tiled -> a3
  conv_tiled<14,14,14,14,1,false><<<dim3(B,8), 256, 0, stream>>>(a2, conv3_w, conv3_b, a3,
                                                                 128, 128, 0, 128, 0, 0);
  // [7] bn3 + elu + avgpool -> p2
  stats_kernel<<<B*128, 256, 0, stream>>>(a3, s3, q3, 128, 196);
  bn_elu_pool_kernel<<<nb((long long)B*128*49), 256, 0, stream>>>(a3, bn3_g, bn3_b, s3, q3, p2,
                                                                  B, 128, 14, 14, 1.f/50176.f);
  // [8] dc41 offsets + mask -> om41
  conv_tiled<7,7,7,7,1,false><<<dim3(B,2), 256, 0, stream>>>(p2, dc41_pw, dc41_pb, om41,
                                                             128, 18, 0, 27, 0, 0);
  conv_tiled<7,7,7,7,1,false><<<dim3(B,1), 256, 0, stream>>>(p2, dc41_mw, dc41_mb, om41,
                                                             128, 9, 0, 27, 18, 1);
  // [9] deform conv 41 (128->64) -> a41
  deform_gemm<128,64,7,7,13,4><<<B*4, 256, 0, stream>>>(p2, om41, dc41_w, a41);
  // [10] bn41 + elu
  stats_kernel<<<B*64, 256, 0, stream>>>(a41, s41, q41, 64, 49);
  bn_elu_inplace_kernel<<<nb((long long)B*64*49), 256, 0, stream>>>(a41, bn41_g, bn41_b, s41, q41,
                                                                    64, 49, 1.f/12544.f, B*64*49);
  // [11] conv4 (64->2, 7x7) naive
  conv3x3_kernel<<<nb((long long)B*2*49), 256, 0, stream>>>(a41, conv4_w, conv4_b, a4,
                                                            B, 64, 2, 7, 7, 2, 0, 0);
  // [12] convT4m: 2->128, s=2, p=1, 7->13 (tiny, naive)
  convt_kernel<<<nb((long long)B*128*169), 256, 0, stream>>>(a4, conv4m_w, conv4m_b, t4m,
                                                             B, 2, 128, 7, 7, 13, 13, 3, 2, 1, 0);
  // [13] convT3m: 128->64, s=1 == conv pad2 w/ flipped transposed weights, +elu
  conv_tiled<13,13,15,15,2,true><<<dim3(B,4), 256, 0, stream>>>(t4m, conv3m_w, conv3m_b, t3m,
                                                                128, 64, 64, 64, 0, 2);
  // [14] convT2m: 64->32, s=2, p=1, 15->29, +elu (naive)
  convt_kernel<<<nb((long long)B*32*841), 256, 0, stream>>>(t3m, conv2m_w, conv2m_b, t2m,
                                                            B, 64, 32, 15, 15, 29, 29, 3, 2, 1, 1);
  // [15] convT1m: 32->2, k=2, s=1, p=1, 29->28, +elu (naive)
  convt_kernel<<<nb((long long)B*2*784), 256, 0, stream>>>(t2m, conv1m_w, conv1m_b, t1m,
                                                           B, 32, 2, 29, 29, 28, 28, 2, 1, 0, 1);
  // [16] final warp
  warp_kernel<<<nb((long long)B*784), 256, 0, stream>>>(t1m, x1, (float*)d_out, B);
}

// Round 5
// 2186.688 us; speedup vs baseline: 3.8674x; 1.4654x over previous
//
#include <hip/hip_runtime.h>
#include <hip/hip_bf16.h>

__device__ __forceinline__ float eluf(float x){ return x > 0.f ? x : expm1f(x); }

// ---------------- naive 3x3 pad-1 conv (kept for conv1 (H=28) and tiny conv4) ----------------
__global__ void conv3x3_kernel(const float* __restrict__ in, const float* __restrict__ w,
                               const float* __restrict__ bias, float* __restrict__ out,
                               int B, int Cin, int Cout, int H, int W, int Ctot, int ooff, int act)
{
  int idx = blockIdx.x*256 + threadIdx.x;
  int total = B*Cout*H*W;
  if (idx >= total) return;
  int x = idx % W; int t = idx / W;
  int y = t % H;   t /= H;
  int o = t % Cout; int b = t / Cout;
  float acc = bias ? bias[o] : 0.f;
  const float* wp = w + (long long)o*Cin*9;
  for (int c = 0; c < Cin; c++){
    const float* ip = in + (long long)(b*Cin + c)*H*W;
    const float* wc = wp + c*9;
    #pragma unroll
    for (int ky = 0; ky < 3; ky++){
      int iy = y + ky - 1; if ((unsigned)iy >= (unsigned)H) continue;
      #pragma unroll
      for (int kx = 0; kx < 3; kx++){
        int ix = x + kx - 1; if ((unsigned)ix >= (unsigned)W) continue;
        acc += wc[ky*3+kx] * ip[iy*W + ix];
      }
    }
  }
  if (act == 1) acc = 1.f/(1.f + expf(-acc));
  out[(((long long)b*Ctot + ooff + o)*H + y)*W + x] = acc;
}

// ---------------- tiled 3x3 conv: block=(b, 16-o tile), 256 thr = 16o x 16y ----------------
template<int HIN,int WIN,int HOUT,int WOUT,int PAD,bool TRANSP>
__global__ __launch_bounds__(256)
void conv_tiled(const float* __restrict__ in, const float* __restrict__ w,
                const float* __restrict__ bias, float* __restrict__ out,
                int Cin, int Cout, int CoutW, int Ctot, int ooff, int act)
{
  constexpr int HP = HIN + 2*PAD, WP = WIN + 2*PAD, WPL = WP + 1;
  __shared__ float img[HP*WPL];
  __shared__ float wl[16*9];
  const int b  = blockIdx.x;
  const int o0 = blockIdx.y * 16;
  const int t  = threadIdx.x;
  const int ol = t >> 4, y = t & 15;
  const bool act_th = (y < HOUT) && (o0 + ol < Cout);
  float acc[WOUT];
  #pragma unroll
  for (int x = 0; x < WOUT; x++) acc[x] = 0.f;
  for (int idx = t; idx < HP*WPL; idx += 256) img[idx] = 0.f;  // zero borders
  const long long inb = (long long)b*Cin*HIN*WIN;
  for (int c = 0; c < Cin; c++){
    __syncthreads();
    for (int idx = t; idx < HIN*WIN; idx += 256){
      int iy = idx / WIN, ix = idx % WIN;
      img[(iy+PAD)*WPL + (ix+PAD)] = in[inb + (long long)c*HIN*WIN + idx];
    }
    if (t < 144){
      int oo = t / 9, kk = t % 9;
      int og = o0 + oo;
      float wv = 0.f;
      if (og < Cout){
        if (TRANSP) wv = w[((long long)c*CoutW + og)*9 + (2 - kk/3)*3 + (2 - kk%3)];
        else        wv = w[((long long)og*Cin + c)*9 + kk];
      }
      wl[t] = wv;
    }
    __syncthreads();
    if (act_th){
      #pragma unroll
      for (int ky = 0; ky < 3; ky++){
        const float* row = &img[(y+ky)*WPL];
        float rin[WOUT+2];
        #pragma unroll
        for (int x = 0; x < WOUT+2; x++) rin[x] = row[x];
        #pragma unroll
        for (int kx = 0; kx < 3; kx++){
          float wv = wl[ol*9 + ky*3 + kx];
          #pragma unroll
          for (int x = 0; x < WOUT; x++) acc[x] += wv * rin[x+kx];
        }
      }
    }
  }
  if (act_th){
    int og = o0 + ol;
    float bv = bias[og];
    #pragma unroll
    for (int x = 0; x < WOUT; x++){
      float v = acc[x] + bv;
      if (act == 1) v = 1.f/(1.f + expf(-v));
      else if (act == 2) v = eluf(v);
      out[(((long long)b*Ctot + ooff + og)*HOUT + y)*WOUT + x] = v;
    }
  }
}

// ---------------- stride-2 transpose conv, parity-decomposed, tiled ----------------
// weight layout (CIN, COUT, 3, 3); out = 2*HIN-1 x 2*WIN-1 (pad=1); elu epilogue.
// block=(b, 16-o tile); 256 thr = 16o x 16 row-pairs. Each thread owns output rows 2yb, 2yb+1.
template<int HIN,int WIN,int CIN,int COUT>
__global__ __launch_bounds__(256)
void convt_s2_tiled(const float* __restrict__ in, const float* __restrict__ w,
                    const float* __restrict__ bias, float* __restrict__ out)
{
  constexpr int HOUT = 2*HIN - 1, WOUT = 2*WIN - 1;
  __shared__ float img[17*16];          // rows 0..HIN-1 staged, stride 16 (b128-aligned)
  __shared__ float wl[16][10];
  const int b  = blockIdx.x;
  const int o0 = blockIdx.y * 16;
  const int t  = threadIdx.x;
  const int ol = t >> 4, yb = t & 15;
  float accA[WOUT], accB[WOUT];
  #pragma unroll
  for (int x = 0; x < WOUT; x++){ accA[x] = 0.f; accB[x] = 0.f; }
  for (int c = 0; c < CIN; c++){
    __syncthreads();
    for (int idx = t; idx < HIN*WIN; idx += 256)
      img[(idx/WIN)*16 + idx%WIN] = in[((long long)b*CIN + c)*HIN*WIN + idx];
    if (t < 144)
      wl[t/9][t%9] = w[(((long long)c*COUT + o0 + t/9)*3 + (t%9)/3)*3 + (t%9)%3];
    __syncthreads();
    float ru[16], rd[16];
    #pragma unroll
    for (int q = 0; q < 4; q++){
      float4 va = ((const float4*)&img[yb*16])[q];
      ru[4*q+0]=va.x; ru[4*q+1]=va.y; ru[4*q+2]=va.z; ru[4*q+3]=va.w;
      float4 vb = ((const float4*)&img[(yb+1)*16])[q];
      rd[4*q+0]=vb.x; rd[4*q+1]=vb.y; rd[4*q+2]=vb.z; rd[4*q+3]=vb.w;
    }
    float w00=wl[ol][0], w01=wl[ol][1], w02=wl[ol][2];
    float w10=wl[ol][3], w11=wl[ol][4], w12=wl[ol][5];
    float w20=wl[ol][6], w21=wl[ol][7], w22=wl[ol][8];
    #pragma unroll
    for (int v = 0; v < WIN; v++){
      accA[2*v] += w11*ru[v];
      accB[2*v] += w21*ru[v] + w01*rd[v];
    }
    #pragma unroll
    for (int v = 0; v < WIN-1; v++){
      accA[2*v+1] += w12*ru[v] + w10*ru[v+1];
      accB[2*v+1] += w22*ru[v] + w20*ru[v+1] + w02*rd[v] + w00*rd[v+1];
    }
  }
  const int og = o0 + ol;
  const float bv = bias[og];
  const int yA = 2*yb, yB = 2*yb + 1;
  if (yA < HOUT){
    float* po = out + (((long long)b*COUT + og)*HOUT + yA)*WOUT;
    #pragma unroll
    for (int x = 0; x < WOUT; x++) po[x] = eluf(accA[x] + bv);
  }
  if (yB < HOUT){
    float* po = out + (((long long)b*COUT + og)*HOUT + yB)*WOUT;
    #pragma unroll
    for (int x = 0; x < WOUT; x++) po[x] = eluf(accB[x] + bv);
  }
}

// ---------------- deformable conv as fused gather-GEMM ----------------
template<int CIN,int COUT,int H,int W,int PXT,int PXG>
__global__ __launch_bounds__(256)
void deform_gemm(const float* __restrict__ x, const float* __restrict__ om,
                 const float* __restrict__ w, float* __restrict__ out)
{
  constexpr int HW = H*W;
  constexpr int NT = (HW + PXT - 1)/PXT;
  constexpr int PPT = (PXT + PXG - 1)/PXG;
  constexpr int PXTP = PPT*PXG;
  __shared__ float simg[8*HW];
  __shared__ float S[72*PXTP];
  __shared__ float kwv[PXT*9*4];
  __shared__ int   kidx[PXT*9*4];
  const int tile = blockIdx.x % NT;
  const int b    = blockIdx.x / NT;
  const int t    = threadIdx.x;
  const int o    = t % COUT;
  const int pxg  = t / COUT;
  const int Hp = H + 2, Wp = W + 2;
  for (int it = t; it < PXT*9; it += 256){
    int px = it / 9, kk = it % 9;
    int p = tile*PXT + px;
    float w0=0.f,w1=0.f,w2=0.f,w3=0.f;
    int i0=0,i1=0,i2=0,i3=0;
    if (p < HW){
      int i = p / W, j = p % W;
      long long base = ((long long)b*27)*HW + p;
      float offx = om[base + (long long)kk*HW];
      float offy = om[base + (long long)(9+kk)*HW];
      float mk   = om[base + (long long)(18+kk)*HW];
      float pnx = (float)(kk/3) - 1.f;
      float pny = (float)(kk%3) - 1.f;
      float px_ = fminf(fmaxf((float)(i+1) + pnx + offx, 0.f), (float)(Hp-1));
      float py_ = fminf(fmaxf((float)(j+1) + pny + offy, 0.f), (float)(Wp-1));
      float fx = floorf(px_), fy = floorf(py_);
      float x0 = fmaxf(fx, 0.f), y0 = fmaxf(fy, 0.f);
      float x1c = fminf(fx + 1.f, (float)(Hp-1));
      float y1c = fminf(fy + 1.f, (float)(Wp-1));
      float glt = (1.f + (x0 - px_)) * (1.f + (y0 - py_));
      float grb = (1.f - (x1c - px_)) * (1.f - (y1c - py_));
      float glb = (1.f + (x0 - px_)) * (1.f - (y1c - py_));
      float grt = (1.f - (x1c - px_)) * (1.f + (y0 - py_));
      int ax0=(int)x0, ay0=(int)y0, ax1=(int)x1c, ay1=(int)y1c;
      if (ax0>=1 && ax0<=H && ay0>=1 && ay0<=W){ w0 = glt*mk; i0 = (ax0-1)*W + (ay0-1); }
      if (ax1>=1 && ax1<=H && ay1>=1 && ay1<=W){ w1 = grb*mk; i1 = (ax1-1)*W + (ay1-1); }
      if (ax0>=1 && ax0<=H && ay1>=1 && ay1<=W){ w2 = glb*mk; i2 = (ax0-1)*W + (ay1-1); }
      if (ax1>=1 && ax1<=H && ay0>=1 && ay0<=W){ w3 = grt*mk; i3 = (ax1-1)*W + (ay0-1); }
    }
    int b4 = it*4;
    kwv[b4+0]=w0; kwv[b4+1]=w1; kwv[b4+2]=w2; kwv[b4+3]=w3;
    kidx[b4+0]=i0; kidx[b4+1]=i1; kidx[b4+2]=i2; kidx[b4+3]=i3;
  }
  float acc[PPT];
  #pragma unroll
  for (int pp = 0; pp < PPT; pp++) acc[pp] = 0.f;
  const float* wrow = w + (long long)o*CIN*9;
  for (int cc = 0; cc < CIN/8; cc++){
    __syncthreads();
    for (int idx = t; idx < 8*HW; idx += 256)
      simg[idx] = x[((long long)b*CIN + cc*8)*HW + idx];
    __syncthreads();
    for (int idx = t; idx < 72*PXT; idx += 256){
      int k = idx / PXT, px = idx % PXT;
      int cl = k / 9, kk = k % 9;
      int b4 = (px*9 + kk)*4;
      const float* im = &simg[cl*HW];
      float v = kwv[b4+0]*im[kidx[b4+0]] + kwv[b4+1]*im[kidx[b4+1]]
              + kwv[b4+2]*im[kidx[b4+2]] + kwv[b4+3]*im[kidx[b4+3]];
      S[k*PXTP + px] = v;
    }
    __syncthreads();
    const float* wc = wrow + cc*72;
    #pragma unroll 4
    for (int k = 0; k < 72; k++){
      float wv = wc[k];
      #pragma unroll
      for (int pp = 0; pp < PPT; pp++)
        acc[pp] += wv * S[k*PXTP + pxg*PPT + pp];
    }
  }
  #pragma unroll
  for (int pp = 0; pp < PPT; pp++){
    int pxl = pxg*PPT + pp;
    int p = tile*PXT + pxl;
    if (pxl < PXT && p < HW)
      out[((long long)b*COUT + o)*HW + p] = acc[pp];
  }
}

// ---------------- per-channel sum / sumsq ----------------
__global__ void stats_kernel(const float* __restrict__ xin, float* __restrict__ sum,
                             float* __restrict__ sq, int C, int HW)
{
  __shared__ float s1[256], s2[256];
  int c = blockIdx.x % C;
  const float* p = xin + (long long)blockIdx.x*HW;
  float a = 0.f, b = 0.f;
  for (int i = threadIdx.x; i < HW; i += 256){ float v = p[i]; a += v; b += v*v; }
  s1[threadIdx.x] = a; s2[threadIdx.x] = b;
  __syncthreads();
  for (int st = 128; st > 0; st >>= 1){
    if (threadIdx.x < st){ s1[threadIdx.x] += s1[threadIdx.x+st]; s2[threadIdx.x] += s2[threadIdx.x+st]; }
    __syncthreads();
  }
  if (threadIdx.x == 0){ atomicAdd(&sum[c], s1[0]); atomicAdd(&sq[c], s2[0]); }
}

// ---------------- bn + elu + 2x2 avgpool ----------------
__global__ void bn_elu_pool_kernel(const float* __restrict__ in, const float* __restrict__ g,
                                   const float* __restrict__ bb, const float* __restrict__ sum,
                                   const float* __restrict__ sq, float* __restrict__ out,
                                   int B, int C, int H, int W, float invN)
{
  int Ho = H/2, Wo = W/2;
  int idx = blockIdx.x*256 + threadIdx.x;
  int total = B*C*Ho*Wo;
  if (idx >= total) return;
  int x = idx % Wo; int t = idx / Wo;
  int y = t % Ho;   t /= Ho;
  int c = t % C;    int b = t / C;
  float mean = sum[c]*invN;
  float var  = sq[c]*invN - mean*mean;
  float sc = g[c] * rsqrtf(var + 1e-5f);
  float sh = bb[c] - mean*sc;
  const float* p = in + (long long)(b*C + c)*H*W;
  float acc = 0.f;
  #pragma unroll
  for (int dy = 0; dy < 2; dy++)
    #pragma unroll
    for (int dx = 0; dx < 2; dx++)
      acc += eluf(sc*p[(2*y+dy)*W + (2*x+dx)] + sh);
  out[idx] = acc * 0.25f;
}

// ---------------- bn + elu in place ----------------
__global__ void bn_elu_inplace_kernel(float* __restrict__ xio, const float* __restrict__ g,
                                      const float* __restrict__ bb, const float* __restrict__ sum,
                                      const float* __restrict__ sq, int C, int HW, float invN, int total)
{
  int idx = blockIdx.x*256 + threadIdx.x;
  if (idx >= total) return;
  int c = (idx / HW) % C;
  float mean = sum[c]*invN;
  float var  = sq[c]*invN - mean*mean;
  float sc = g[c] * rsqrtf(var + 1e-5f);
  float sh = bb[c] - mean*sc;
  xio[idx] = eluf(sc*xio[idx] + sh);
}

// ---------------- generic transpose conv (kept for convT4m/convT1m) ----------------
__global__ void convt_kernel(const float* __restrict__ in, const float* __restrict__ w,
                             const float* __restrict__ bias, float* __restrict__ out,
                             int B, int Cin, int Cout, int Hin, int Win, int Hout, int Wout,
                             int K, int S, int PP, int do_elu)
{
  int idx = blockIdx.x*256 + threadIdx.x;
  int total = B*Cout*Hout*Wout;
  if (idx >= total) return;
  int x = idx % Wout; int t = idx / Wout;
  int y = t % Hout;   t /= Hout;
  int o = t % Cout;   int b = t / Cout;
  float acc = bias[o];
  for (int ky = 0; ky < K; ky++){
    int dy = y + ky - PP;
    if (dy < 0 || (dy % S) != 0) continue;
    int iy = dy / S; if (iy >= Hin) continue;
    int wky = K - 1 - ky;
    for (int kx = 0; kx < K; kx++){
      int dx = x + kx - PP;
      if (dx < 0 || (dx % S) != 0) continue;
      int ix = dx / S; if (ix >= Win) continue;
      int wkx = K - 1 - kx;
      const float* ip = in + (long long)b*Cin*Hin*Win + (long long)iy*Win + ix;
      for (int c = 0; c < Cin; c++){
        acc += w[(((long long)c*Cout + o)*K + wky)*K + wkx] * ip[(long long)c*Hin*Win];
      }
    }
  }
  if (do_elu) acc = eluf(acc);
  out[idx] = acc;
}

// ---------------- final bicubic warp ----------------
__device__ __forceinline__ float cubicf(float A, float Bv, float C, float D, float t){
  float a = -0.5f*A + 1.5f*Bv - 1.5f*C + 0.5f*D;
  float b =  A - 2.5f*Bv + 2.0f*C - 0.5f*D;
  float c = -0.5f*A + 0.5f*C;
  return ((a*t + b)*t + c)*t + Bv;
}

__global__ void warp_kernel(const float* __restrict__ V, const float* __restrict__ x1,
                            float* __restrict__ out, int B)
{
  int idx = blockIdx.x*256 + threadIdx.x;
  int total = B*784;
  if (idx >= total) return;
  int j = idx % 28; int t = idx / 28;
  int i = t % 28;   int b = t / 28;
  float v0 = V[((long long)b*2 + 0)*784 + j*28 + i];
  float v1 = V[((long long)b*2 + 1)*784 + j*28 + i];
  float gx = (-1.f + 2.f*(float)j/27.f) + v0;
  float gy = (-1.f + 2.f*(float)i/27.f) + v1;
  float ix = (gx + 1.f)*13.5f;
  float iy = (gy + 1.f)*13.5f;
  float x0 = floorf(ix), y0 = floorf(iy);
  float tx = ix - x0, ty = iy - y0;
  const float* img = x1 + (long long)b*2*784;
  float rows[4];
  #pragma unroll
  for (int ky = -1; ky <= 2; ky++){
    int yi = (int)fminf(fmaxf(y0 + (float)ky, 0.f), 27.f);
    float cv[4];
    #pragma unroll
    for (int kx = -1; kx <= 2; kx++){
      int xi = (int)fminf(fmaxf(x0 + (float)kx, 0.f), 27.f);
      cv[kx+1] = img[yi*28 + xi];
    }
    rows[ky+1] = cubicf(cv[0], cv[1], cv[2], cv[3], tx);
  }
  out[idx] = cubicf(rows[0], rows[1], rows[2], rows[3], ty);
}

// ---------------- host ----------------
extern "C" void kernel_launch(void* const* d_in, const int* in_sizes, int n_in,
                              void* d_out, int out_size, void* d_ws, size_t ws_size,
                              hipStream_t stream)
{
  const int B = 256;
  const float* x1      = (const float*)d_in[0];
  const float* conv1_w = (const float*)d_in[9];
  const float* conv1_b = (const float*)d_in[10];
  const float* bn1_g   = (const float*)d_in[11];
  const float* bn1_b   = (const float*)d_in[12];
  const float* dc2_pw  = (const float*)d_in[13];
  const float* dc2_pb  = (const float*)d_in[14];
  const float* dc2_mw  = (const float*)d_in[15];
  const float* dc2_mb  = (const float*)d_in[16];
  const float* dc2_w   = (const float*)d_in[17];
  const float* bn2_g   = (const float*)d_in[18];
  const float* bn2_b   = (const float*)d_in[19];
  const float* conv3_w = (const float*)d_in[20];
  const float* conv3_b = (const float*)d_in[21];
  const float* bn3_g   = (const float*)d_in[22];
  const float* bn3_b   = (const float*)d_in[23];
  const float* dc41_pw = (const float*)d_in[24];
  const float* dc41_pb = (const float*)d_in[25];
  const float* dc41_mw = (const float*)d_in[26];
  const float* dc41_mb = (const float*)d_in[27];
  const float* dc41_w  = (const float*)d_in[28];
  const float* bn41_g  = (const float*)d_in[29];
  const float* bn41_b  = (const float*)d_in[30];
  const float* conv4_w = (const float*)d_in[31];
  const float* conv4_b = (const float*)d_in[32];
  const float* conv4m_w= (const float*)d_in[33];
  const float* conv4m_b= (const float*)d_in[34];
  const float* conv3m_w= (const float*)d_in[35];
  const float* conv3m_b= (const float*)d_in[36];
  const float* conv2m_w= (const float*)d_in[37];
  const float* conv2m_b= (const float*)d_in[38];
  const float* conv1m_w= (const float*)d_in[39];
  const float* conv1m_b= (const float*)d_in[40];

  float* ws = (float*)d_ws;

  // lifetime-packed arena (floats), stats in [0,1024)
  const long long AB = 1024;
  float* p1   = ws + AB;               // live [2..4]
  float* a1   = ws + AB + 3211264;     // live [1..2]
  float* om2  = ws + AB + 3211264;     // live [3..4]
  float* a2   = ws + AB + 4566016;     // live [4..6]
  float* a3   = ws + AB + 10988544;    // live [6..7]
  float* p2   = ws + AB;               // live [7..9]
  float* om41 = ws + AB + 1605632;     // live [8..9]
  float* a41  = ws + AB + 1944320;     // live [9..11]
  float* a4   = ws + AB + 2747136;     // live [11..12]
  float* t4m  = ws + AB + 2772224;     // live [12..13]
  float* t3m  = ws + AB + 8310016;     // live [13..14]
  float* t2m  = ws + AB + 11996416;    // live [14..15]
  float* t1m  = ws + AB;               // live [15..16]

  float* s1  = ws + 0;   float* q1  = ws + 64;
  float* s2  = ws + 128; float* q2  = ws + 256;
  float* s3  = ws + 384; float* q3  = ws + 512;
  float* s41 = ws + 640; float* q41 = ws + 704;

  auto nb = [](long long n){ return (int)((n + 255)/256); };

  hipMemsetAsync(d_ws, 0, 4096, stream);

  // [1] conv1 (2->64, 28x28) naive
  conv3x3_kernel<<<nb((long long)B*64*784), 256, 0, stream>>>(x1, conv1_w, conv1_b, a1,
                                                              B, 2, 64, 28, 28, 64, 0, 0);
  // [2] bn1 + elu + avgpool -> p1
  stats_kernel<<<B*64, 256, 0, stream>>>(a1, s1, q1, 64, 784);
  bn_elu_pool_kernel<<<nb((long long)B*64*196), 256, 0, stream>>>(a1, bn1_g, bn1_b, s1, q1, p1,
                                                                  B, 64, 28, 28, 1.f/200704.f);
  // [3] dc2 offsets (64->18) + mask (64->9, sigmoid) -> om2
  conv_tiled<14,14,14,14,1,false><<<dim3(B,2), 256, 0, stream>>>(p1, dc2_pw, dc2_pb, om2,
                                                                 64, 18, 0, 27, 0, 0);
  conv_tiled<14,14,14,14,1,false><<<dim3(B,1), 256, 0, stream>>>(p1, dc2_mw, dc2_mb, om2,
                                                                 64, 9, 0, 27, 18, 1);
  // [4] deform conv 2 (64->128) -> a2
  deform_gemm<64,128,14,14,49,2><<<B*4, 256, 0, stream>>>(p1, om2, dc2_w, a2);
  // [5] bn2 + elu
  stats_kernel<<<B*128, 256, 0, stream>>>(a2, s2, q2, 128, 196);
  bn_elu_inplace_kernel<<<nb((long long)B*128*196), 256, 0, stream>>>(a2, bn2_g, bn2_b, s2, q2,
                                                                      128, 196, 1.f/50176.f, B*128*196);
  // [6] conv3 (128->128) tiled -> a3
  conv_tiled<14,14,14,14,1,false><<<dim3(B,8), 256, 0, stream>>>(a2, conv3_w, conv3_b, a3,
                                                                 128, 128, 0, 128, 0, 0);
  // [7] bn3 + elu + avgpool -> p2
  stats_kernel<<<B*128, 256, 0, stream>>>(a3, s3, q3, 128, 196);
  bn_elu_pool_kernel<<<nb((long long)B*128*49), 256, 0, stream>>>(a3, bn3_g, bn3_b, s3, q3, p2,
                                                                  B, 128, 14, 14, 1.f/50176.f);
  // [8] dc41 offsets + mask -> om41
  conv_tiled<7,7,7,7,1,false><<<dim3(B,2), 256, 0, stream>>>(p2, dc41_pw, dc41_pb, om41,
                                                             128, 18, 0, 27, 0, 0);
  conv_tiled<7,7,7,7,1,false><<<dim3(B,1), 256, 0, stream>>>(p2, dc41_mw, dc41_mb, om41,
                                                             128, 9, 0, 27, 18, 1);
  // [9] deform conv 41 (128->64) -> a41
  deform_gemm<128,64,7,7,13,4><<<B*4, 256, 0, stream>>>(p2, om41, dc41_w, a41);
  // [10] bn41 + elu
  stats_kernel<<<B*64, 256, 0, stream>>>(a41, s41, q41, 64, 49);
  bn_elu_inplace_kernel<<<nb((long long)B*64*49), 256, 0, stream>>>(a41, bn41_g, bn41_b, s41, q41,
                                                                    64, 49, 1.f/12544.f, B*64*49);
  // [11] conv4 (64->2, 7x7) naive
  conv3x3_kernel<<<nb((long long)B*2*49), 256, 0, stream>>>(a41, conv4_w, conv4_b, a4,
                                                            B, 64, 2, 7, 7, 2, 0, 0);
  // [12] convT4m: 2->128, s=2, p=1, 7->13 (tiny, naive)
  convt_kernel<<<nb((long long)B*128*169), 256, 0, stream>>>(a4, conv4m_w, conv4m_b, t4m,
                                                             B, 2, 128, 7, 7, 13, 13, 3, 2, 1, 0);
  // [13] convT3m: 128->64, s=1 == conv pad2 w/ flipped transposed weights, +elu
  conv_tiled<13,13,15,15,2,true><<<dim3(B,4), 256, 0, stream>>>(t4m, conv3m_w, conv3m_b, t3m,
                                                                128, 64, 64, 64, 0, 2);
  // [14] convT2m: 64->32, s=2, p=1, 15->29, +elu — parity-decomposed tiled
  convt_s2_tiled<15,15,64,32><<<dim3(B,2), 256, 0, stream>>>(t3m, conv2m_w, conv2m_b, t2m);
  // [15] convT1m: 32->2, k=2, s=1, p=1, 29->28, +elu (naive)
  convt_kernel<<<nb((long long)B*2*784), 256, 0, stream>>>(t2m, conv1m_w, conv1m_b, t1m,
                                                           B, 32, 2, 29, 29, 28, 28, 2, 1, 0, 1);
  // [16] final warp
  warp_kernel<<<nb((long long)B*784), 256, 0, stream>>>(t1m, x1, (float*)d_out, B);
}

// Round 7
// 1871.502 us; speedup vs baseline: 4.5188x; 1.1684x over previous
//
#include <hip/hip_runtime.h>
#include <hip/hip_bf16.h>

__device__ __forceinline__ float eluf(float x){ return x > 0.f ? x : expm1f(x); }

// ---------------- naive 3x3 pad-1 conv (kept only for tiny conv4) ----------------
__global__ void conv3x3_kernel(const float* __restrict__ in, const float* __restrict__ w,
                               const float* __restrict__ bias, float* __restrict__ out,
                               int B, int Cin, int Cout, int H, int W, int Ctot, int ooff, int act)
{
  int idx = blockIdx.x*256 + threadIdx.x;
  int total = B*Cout*H*W;
  if (idx >= total) return;
  int x = idx % W; int t = idx / W;
  int y = t % H;   t /= H;
  int o = t % Cout; int b = t / Cout;
  float acc = bias ? bias[o] : 0.f;
  const float* wp = w + (long long)o*Cin*9;
  for (int c = 0; c < Cin; c++){
    const float* ip = in + (long long)(b*Cin + c)*H*W;
    const float* wc = wp + c*9;
    #pragma unroll
    for (int ky = 0; ky < 3; ky++){
      int iy = y + ky - 1; if ((unsigned)iy >= (unsigned)H) continue;
      #pragma unroll
      for (int kx = 0; kx < 3; kx++){
        int ix = x + kx - 1; if ((unsigned)ix >= (unsigned)W) continue;
        acc += wc[ky*3+kx] * ip[iy*W + ix];
      }
    }
  }
  if (act == 1) acc = 1.f/(1.f + expf(-acc));
  out[(((long long)b*Ctot + ooff + o)*H + y)*W + x] = acc;
}

// ---------------- conv1: 2->64, 28x28, fused bn-stats ----------------
// block=(b, 8-o tile); 256 thr = 8o x 32y
__global__ __launch_bounds__(256)
void conv1_tiled(const float* __restrict__ in, const float* __restrict__ w,
                 const float* __restrict__ bias, float* __restrict__ out,
                 float* __restrict__ sum, float* __restrict__ sq)
{
  __shared__ float img[2][30*31];
  __shared__ float wl[2][8*9];
  const int b = blockIdx.x, o0 = blockIdx.y*8, t = threadIdx.x;
  const int ol = t >> 5, y = t & 31;
  for (int idx = t; idx < 2*930; idx += 256) ((float*)img)[idx] = 0.f;
  __syncthreads();
  for (int idx = t; idx < 2*784; idx += 256){
    int cl = idx/784, r = idx%784;
    img[cl][(r/28 + 1)*31 + (r%28) + 1] = in[((long long)b*2)*784 + idx];
  }
  if (t < 144){
    int cl = t/72, r = t%72;
    wl[cl][r] = w[(((long long)(o0 + r/9))*2 + cl)*9 + (r%9)];
  }
  __syncthreads();
  const bool active = (y < 28);
  float acc[28];
  #pragma unroll
  for (int x = 0; x < 28; x++) acc[x] = 0.f;
  if (active){
    for (int cl = 0; cl < 2; cl++){
      #pragma unroll
      for (int ky = 0; ky < 3; ky++){
        const float* row = &img[cl][(y+ky)*31];
        float rin[30];
        #pragma unroll
        for (int x = 0; x < 30; x++) rin[x] = row[x];
        #pragma unroll
        for (int kx = 0; kx < 3; kx++){
          float wv = wl[cl][ol*9 + ky*3 + kx];
          #pragma unroll
          for (int x = 0; x < 28; x++) acc[x] += wv * rin[x+kx];
        }
      }
    }
  }
  const int og = o0 + ol;
  float sv = 0.f, qv = 0.f;
  if (active){
    float bv = bias[og];
    float* po = out + (((long long)b*64 + og)*28 + y)*28;
    #pragma unroll
    for (int x = 0; x < 28; x++){
      float v = acc[x] + bv;
      po[x] = v;
      sv += v; qv += v*v;
    }
  }
  #pragma unroll
  for (int d = 16; d > 0; d >>= 1){
    sv += __shfl_down(sv, d, 32);
    qv += __shfl_down(qv, d, 32);
  }
  if (y == 0){ atomicAdd(&sum[og], sv); atomicAdd(&sq[og], qv); }
}

// ---------------- tiled 3x3 conv, CS channels per barrier, optional fused stats ----------------
template<int HIN,int WIN,int HOUT,int WOUT,int PAD,bool TRANSP,int CS>
__global__ __launch_bounds__(256)
void conv_tiled_cs(const float* __restrict__ in, const float* __restrict__ w,
                   const float* __restrict__ bias, float* __restrict__ out,
                   float* __restrict__ sum, float* __restrict__ sq,
                   int Cin, int Cout, int CoutW, int Ctot, int ooff, int act)
{
  constexpr int HP = HIN + 2*PAD, WP = WIN + 2*PAD, WPL = WP + 1;
  __shared__ float img[CS][HP*WPL];
  __shared__ float wl[CS][16*9];
  const int b  = blockIdx.x;
  const int o0 = blockIdx.y * 16;
  const int t  = threadIdx.x;
  const int ol = t >> 4, y = t & 15;
  const bool act_th = (y < HOUT) && (o0 + ol < Cout);
  float acc[WOUT];
  #pragma unroll
  for (int x = 0; x < WOUT; x++) acc[x] = 0.f;
  for (int idx = t; idx < CS*HP*WPL; idx += 256) ((float*)img)[idx] = 0.f;
  const long long inb = (long long)b*Cin*HIN*WIN;
  for (int c0 = 0; c0 < Cin; c0 += CS){
    __syncthreads();
    for (int idx = t; idx < CS*HIN*WIN; idx += 256){
      int cl = idx/(HIN*WIN), r = idx%(HIN*WIN);
      img[cl][(r/WIN + PAD)*WPL + (r%WIN) + PAD] = in[inb + (long long)c0*HIN*WIN + idx];
    }
    for (int idx = t; idx < CS*144; idx += 256){
      int cl = idx/144, r = idx%144, oo = r/9, kk = r%9;
      int og = o0 + oo;
      float wv = 0.f;
      if (og < Cout){
        int c = c0 + cl;
        if (TRANSP) wv = w[((long long)c*CoutW + og)*9 + (2 - kk/3)*3 + (2 - kk%3)];
        else        wv = w[((long long)og*Cin + c)*9 + kk];
      }
      wl[cl][r] = wv;
    }
    __syncthreads();
    if (act_th){
      for (int cl = 0; cl < CS; cl++){
        #pragma unroll
        for (int ky = 0; ky < 3; ky++){
          const float* row = &img[cl][(y+ky)*WPL];
          float rin[WOUT+2];
          #pragma unroll
          for (int x = 0; x < WOUT+2; x++) rin[x] = row[x];
          #pragma unroll
          for (int kx = 0; kx < 3; kx++){
            float wv = wl[cl][ol*9 + ky*3 + kx];
            #pragma unroll
            for (int x = 0; x < WOUT; x++) acc[x] += wv * rin[x+kx];
          }
        }
      }
    }
  }
  const int og = o0 + ol;
  float sv = 0.f, qv = 0.f;
  if (act_th){
    float bv = bias[og];
    float* po = out + (((long long)b*Ctot + ooff + og)*HOUT + y)*WOUT;
    #pragma unroll
    for (int x = 0; x < WOUT; x++){
      float v = acc[x] + bv;
      float vw = v;
      if (act == 1) vw = 1.f/(1.f + expf(-v));
      else if (act == 2) vw = eluf(v);
      po[x] = vw;
      sv += v; qv += v*v;
    }
  }
  if (sum){
    #pragma unroll
    for (int d = 8; d > 0; d >>= 1){
      sv += __shfl_down(sv, d, 16);
      qv += __shfl_down(qv, d, 16);
    }
    if (y == 0 && og < Cout){ atomicAdd(&sum[og], sv); atomicAdd(&sq[og], qv); }
  }
}

// ---------------- stride-2 transpose conv, parity-decomposed ----------------
template<int HIN,int WIN,int CIN,int COUT,bool DO_ELU>
__global__ __launch_bounds__(256)
void convt_s2_tiled(const float* __restrict__ in, const float* __restrict__ w,
                    const float* __restrict__ bias, float* __restrict__ out)
{
  constexpr int HOUT = 2*HIN - 1, WOUT = 2*WIN - 1;
  __shared__ float img[17*16];
  __shared__ float wl[16][10];
  const int b  = blockIdx.x;
  const int o0 = blockIdx.y * 16;
  const int t  = threadIdx.x;
  const int ol = t >> 4, yb = t & 15;
  for (int idx = t; idx < 17*16; idx += 256) img[idx] = 0.f;
  float accA[WOUT], accB[WOUT];
  #pragma unroll
  for (int x = 0; x < WOUT; x++){ accA[x] = 0.f; accB[x] = 0.f; }
  for (int c = 0; c < CIN; c++){
    __syncthreads();
    for (int idx = t; idx < HIN*WIN; idx += 256)
      img[(idx/WIN)*16 + idx%WIN] = in[((long long)b*CIN + c)*HIN*WIN + idx];
    if (t < 144)
      wl[t/9][t%9] = w[(((long long)c*COUT + o0 + t/9)*3 + (t%9)/3)*3 + (t%9)%3];
    __syncthreads();
    float ru[16], rd[16];
    #pragma unroll
    for (int q = 0; q < 4; q++){
      float4 va = ((const float4*)&img[yb*16])[q];
      ru[4*q+0]=va.x; ru[4*q+1]=va.y; ru[4*q+2]=va.z; ru[4*q+3]=va.w;
      float4 vb = ((const float4*)&img[(yb+1)*16])[q];
      rd[4*q+0]=vb.x; rd[4*q+1]=vb.y; rd[4*q+2]=vb.z; rd[4*q+3]=vb.w;
    }
    float w00=wl[ol][0], w01=wl[ol][1], w02=wl[ol][2];
    float w10=wl[ol][3], w11=wl[ol][4], w12=wl[ol][5];
    float w20=wl[ol][6], w21=wl[ol][7], w22=wl[ol][8];
    #pragma unroll
    for (int v = 0; v < WIN; v++){
      accA[2*v] += w11*ru[v];
      accB[2*v] += w21*ru[v] + w01*rd[v];
    }
    #pragma unroll
    for (int v = 0; v < WIN-1; v++){
      accA[2*v+1] += w12*ru[v] + w10*ru[v+1];
      accB[2*v+1] += w22*ru[v] + w20*ru[v+1] + w02*rd[v] + w00*rd[v+1];
    }
  }
  const int og = o0 + ol;
  const float bv = bias[og];
  const int yA = 2*yb, yB = 2*yb + 1;
  if (yA < HOUT){
    float* po = out + (((long long)b*COUT + og)*HOUT + yA)*WOUT;
    #pragma unroll
    for (int x = 0; x < WOUT; x++){ float v = accA[x] + bv; po[x] = DO_ELU ? eluf(v) : v; }
  }
  if (yB < HOUT){
    float* po = out + (((long long)b*COUT + og)*HOUT + yB)*WOUT;
    #pragma unroll
    for (int x = 0; x < WOUT; x++){ float v = accB[x] + bv; po[x] = DO_ELU ? eluf(v) : v; }
  }
}

// ---------------- deform weight transpose: w[o][c][kk] -> wT[cc][cl*9+kk][o] ----------------
__global__ void wtrans_kernel(const float* __restrict__ w, float* __restrict__ wT,
                              int CIN, int COUT)
{
  int n = CIN*COUT*9;
  int idx = blockIdx.x*256 + threadIdx.x;
  if (idx >= n) return;
  int cc = idx / (72*COUT);
  int r  = idx % (72*COUT);
  int k  = r / COUT, o = r % COUT;
  int c  = cc*8 + k/9, kk = k%9;
  wT[idx] = w[((long long)o*CIN + c)*9 + kk];
}

// ---------------- deformable conv, fused gather-GEMM, transposed weights, fused stats ----------------
template<int CIN,int COUT,int H,int W,int PXT,int PXG>
__global__ __launch_bounds__(256)
void deform_gemm(const float* __restrict__ x, const float* __restrict__ om,
                 const float* __restrict__ wT, float* __restrict__ out,
                 float* __restrict__ sum, float* __restrict__ sq)
{
  constexpr int HW = H*W;
  constexpr int NT = (HW + PXT - 1)/PXT;
  constexpr int PPT = (PXT + PXG - 1)/PXG;
  constexpr int PXTP = PPT*PXG;
  __shared__ float simg[8*HW];
  __shared__ float S[72*PXTP];
  __shared__ float kwv[PXT*9*4];
  __shared__ int   kidx[PXT*9*4];
  __shared__ float red[512];
  const int tile = blockIdx.x % NT;
  const int b    = blockIdx.x / NT;
  const int t    = threadIdx.x;
  const int o    = t % COUT;
  const int pxg  = t / COUT;
  const int Hp = H + 2, Wp = W + 2;
  for (int it = t; it < PXT*9; it += 256){
    int px = it / 9, kk = it % 9;
    int p = tile*PXT + px;
    float w0=0.f,w1=0.f,w2=0.f,w3=0.f;
    int i0=0,i1=0,i2=0,i3=0;
    if (p < HW){
      int i = p / W, j = p % W;
      long long base = ((long long)b*27)*HW + p;
      float offx = om[base + (long long)kk*HW];
      float offy = om[base + (long long)(9+kk)*HW];
      float mk   = om[base + (long long)(18+kk)*HW];
      float pnx = (float)(kk/3) - 1.f;
      float pny = (float)(kk%3) - 1.f;
      float px_ = fminf(fmaxf((float)(i+1) + pnx + offx, 0.f), (float)(Hp-1));
      float py_ = fminf(fmaxf((float)(j+1) + pny + offy, 0.f), (float)(Wp-1));
      float fx = floorf(px_), fy = floorf(py_);
      float x0 = fmaxf(fx, 0.f), y0 = fmaxf(fy, 0.f);
      float x1c = fminf(fx + 1.f, (float)(Hp-1));
      float y1c = fminf(fy + 1.f, (float)(Wp-1));
      float glt = (1.f + (x0 - px_)) * (1.f + (y0 - py_));
      float grb = (1.f - (x1c - px_)) * (1.f - (y1c - py_));
      float glb = (1.f + (x0 - px_)) * (1.f - (y1c - py_));
      float grt = (1.f - (x1c - px_)) * (1.f + (y0 - py_));
      int ax0=(int)x0, ay0=(int)y0, ax1=(int)x1c, ay1=(int)y1c;
      if (ax0>=1 && ax0<=H && ay0>=1 && ay0<=W){ w0 = glt*mk; i0 = (ax0-1)*W + (ay0-1); }
      if (ax1>=1 && ax1<=H && ay1>=1 && ay1<=W){ w1 = grb*mk; i1 = (ax1-1)*W + (ay1-1); }
      if (ax0>=1 && ax0<=H && ay1>=1 && ay1<=W){ w2 = glb*mk; i2 = (ax0-1)*W + (ay1-1); }
      if (ax1>=1 && ax1<=H && ay0>=1 && ay0<=W){ w3 = grt*mk; i3 = (ax1-1)*W + (ay0-1); }
    }
    int b4 = it*4;
    kwv[b4+0]=w0; kwv[b4+1]=w1; kwv[b4+2]=w2; kwv[b4+3]=w3;
    kidx[b4+0]=i0; kidx[b4+1]=i1; kidx[b4+2]=i2; kidx[b4+3]=i3;
  }
  float acc[PPT];
  #pragma unroll
  for (int pp = 0; pp < PPT; pp++) acc[pp] = 0.f;
  for (int cc = 0; cc < CIN/8; cc++){
    __syncthreads();
    for (int idx = t; idx < 8*HW; idx += 256)
      simg[idx] = x[((long long)b*CIN + cc*8)*HW + idx];
    __syncthreads();
    for (int idx = t; idx < 72*PXT; idx += 256){
      int k = idx / PXT, px = idx % PXT;
      int b4 = (px*9 + (k%9))*4;
      const float* im = &simg[(k/9)*HW];
      float v = kwv[b4+0]*im[kidx[b4+0]] + kwv[b4+1]*im[kidx[b4+1]]
              + kwv[b4+2]*im[kidx[b4+2]] + kwv[b4+3]*im[kidx[b4+3]];
      S[k*PXTP + px] = v;
    }
    __syncthreads();
    const float* wc = wT + (long long)cc*72*COUT;
    #pragma unroll 4
    for (int k = 0; k < 72; k++){
      float wv = wc[k*COUT + o];
      #pragma unroll
      for (int pp = 0; pp < PPT; pp++)
        acc[pp] += wv * S[k*PXTP + pxg*PPT + pp];
    }
  }
  float sv = 0.f, qv = 0.f;
  #pragma unroll
  for (int pp = 0; pp < PPT; pp++){
    int pxl = pxg*PPT + pp;
    int p = tile*PXT + pxl;
    if (pxl < PXT && p < HW){
      out[((long long)b*COUT + o)*HW + p] = acc[pp];
      sv += acc[pp]; qv += acc[pp]*acc[pp];
    }
  }
  red[t] = sv; red[256 + t] = qv;
  __syncthreads();
  if (t < COUT){
    float S2 = 0.f, Q2 = 0.f;
    #pragma unroll
    for (int g = 0; g < PXG; g++){ S2 += red[g*COUT + t]; Q2 += red[256 + g*COUT + t]; }
    atomicAdd(&sum[t], S2); atomicAdd(&sq[t], Q2);
  }
}

// ---------------- bn + elu + 2x2 avgpool ----------------
__global__ void bn_elu_pool_kernel(const float* __restrict__ in, const float* __restrict__ g,
                                   const float* __restrict__ bb, const float* __restrict__ sum,
                                   const float* __restrict__ sq, float* __restrict__ out,
                                   int B, int C, int H, int W, float invN)
{
  int Ho = H/2, Wo = W/2;
  int idx = blockIdx.x*256 + threadIdx.x;
  int total = B*C*Ho*Wo;
  if (idx >= total) return;
  int x = idx % Wo; int t = idx / Wo;
  int y = t % Ho;   t /= Ho;
  int c = t % C;    int b = t / C;
  float mean = sum[c]*invN;
  float var  = sq[c]*invN - mean*mean;
  float sc = g[c] * rsqrtf(var + 1e-5f);
  float sh = bb[c] - mean*sc;
  const float* p = in + (long long)(b*C + c)*H*W;
  float acc = 0.f;
  #pragma unroll
  for (int dy = 0; dy < 2; dy++)
    #pragma unroll
    for (int dx = 0; dx < 2; dx++)
      acc += eluf(sc*p[(2*y+dy)*W + (2*x+dx)] + sh);
  out[idx] = acc * 0.25f;
}

// ---------------- bn + elu in place ----------------
__global__ void bn_elu_inplace_kernel(float* __restrict__ xio, const float* __restrict__ g,
                                      const float* __restrict__ bb, const float* __restrict__ sum,
                                      const float* __restrict__ sq, int C, int HW, float invN, int total)
{
  int idx = blockIdx.x*256 + threadIdx.x;
  if (idx >= total) return;
  int c = (idx / HW) % C;
  float mean = sum[c]*invN;
  float var  = sq[c]*invN - mean*mean;
  float sc = g[c] * rsqrtf(var + 1e-5f);
  float sh = bb[c] - mean*sc;
  xio[idx] = eluf(sc*xio[idx] + sh);
}

// ---------------- generic transpose conv (kept for convT1m) ----------------
__global__ void convt_kernel(const float* __restrict__ in, const float* __restrict__ w,
                             const float* __restrict__ bias, float* __restrict__ out,
                             int B, int Cin, int Cout, int Hin, int Win, int Hout, int Wout,
                             int K, int S, int PP, int do_elu)
{
  int idx = blockIdx.x*256 + threadIdx.x;
  int total = B*Cout*Hout*Wout;
  if (idx >= total) return;
  int x = idx % Wout; int t = idx / Wout;
  int y = t % Hout;   t /= Hout;
  int o = t % Cout;   int b = t / Cout;
  float acc = bias[o];
  for (int ky = 0; ky < K; ky++){
    int dy = y + ky - PP;
    if (dy < 0 || (dy % S) != 0) continue;
    int iy = dy / S; if (iy >= Hin) continue;
    int wky = K - 1 - ky;
    for (int kx = 0; kx < K; kx++){
      int dx = x + kx - PP;
      if (dx < 0 || (dx % S) != 0) continue;
      int ix = dx / S; if (ix >= Win) continue;
      int wkx = K - 1 - kx;
      const float* ip = in + (long long)b*Cin*Hin*Win + (long long)iy*Win + ix;
      for (int c = 0; c < Cin; c++){
        acc += w[(((long long)c*Cout + o)*K + wky)*K + wkx] * ip[(long long)c*Hin*Win];
      }
    }
  }
  if (do_elu) acc = eluf(acc);
  out[idx] = acc;
}

// ---------------- final bicubic warp ----------------
__device__ __forceinline__ float cubicf(float A, float Bv, float C, float D, float t){
  float a = -0.5f*A + 1.5f*Bv - 1.5f*C + 0.5f*D;
  float b =  A - 2.5f*Bv + 2.0f*C - 0.5f*D;
  float c = -0.5f*A + 0.5f*C;
  return ((a*t + b)*t + c)*t + Bv;
}

__global__ void warp_kernel(const float* __restrict__ V, const float* __restrict__ x1,
                            float* __restrict__ out, int B)
{
  int idx = blockIdx.x*256 + threadIdx.x;
  int total = B*784;
  if (idx >= total) return;
  int j = idx % 28; int t = idx / 28;
  int i = t % 28;   int b = t / 28;
  float v0 = V[((long long)b*2 + 0)*784 + j*28 + i];
  float v1 = V[((long long)b*2 + 1)*784 + j*28 + i];
  float gx = (-1.f + 2.f*(float)j/27.f) + v0;
  float gy = (-1.f + 2.f*(float)i/27.f) + v1;
  float ix = (gx + 1.f)*13.5f;
  float iy = (gy + 1.f)*13.5f;
  float x0 = floorf(ix), y0 = floorf(iy);
  float tx = ix - x0, ty = iy - y0;
  const float* img = x1 + (long long)b*2*784;
  float rows[4];
  #pragma unroll
  for (int ky = -1; ky <= 2; ky++){
    int yi = (int)fminf(fmaxf(y0 + (float)ky, 0.f), 27.f);
    float cv[4];
    #pragma unroll
    for (int kx = -1; kx <= 2; kx++){
      int xi = (int)fminf(fmaxf(x0 + (float)kx, 0.f), 27.f);
      cv[kx+1] = img[yi*28 + xi];
    }
    rows[ky+1] = cubicf(cv[0], cv[1], cv[2], cv[3], tx);
  }
  out[idx] = cubicf(rows[0], rows[1], rows[2], rows[3], ty);
}

// ---------------- host ----------------
extern "C" void kernel_launch(void* const* d_in, const int* in_sizes, int n_in,
                              void* d_out, int out_size, void* d_ws, size_t ws_size,
                              hipStream_t stream)
{
  const int B = 256;
  const float* x1      = (const float*)d_in[0];
  const float* conv1_w = (const float*)d_in[9];
  const float* conv1_b = (const float*)d_in[10];
  const float* bn1_g   = (const float*)d_in[11];
  const float* bn1_b   = (const float*)d_in[12];
  const float* dc2_pw  = (const float*)d_in[13];
  const float* dc2_pb  = (const float*)d_in[14];
  const float* dc2_mw  = (const float*)d_in[15];
  const float* dc2_mb  = (const float*)d_in[16];
  const float* dc2_w   = (const float*)d_in[17];
  const float* bn2_g   = (const float*)d_in[18];
  const float* bn2_b   = (const float*)d_in[19];
  const float* conv3_w = (const float*)d_in[20];
  const float* conv3_b = (const float*)d_in[21];
  const float* bn3_g   = (const float*)d_in[22];
  const float* bn3_b   = (const float*)d_in[23];
  const float* dc41_pw = (const float*)d_in[24];
  const float* dc41_pb = (const float*)d_in[25];
  const float* dc41_mw = (const float*)d_in[26];
  const float* dc41_mb = (const float*)d_in[27];
  const float* dc41_w  = (const float*)d_in[28];
  const float* bn41_g  = (const float*)d_in[29];
  const float* bn41_b  = (const float*)d_in[30];
  const float* conv4_w = (const float*)d_in[31];
  const float* conv4_b = (const float*)d_in[32];
  const float* conv4m_w= (const float*)d_in[33];
  const float* conv4m_b= (const float*)d_in[34];
  const float* conv3m_w= (const float*)d_in[35];
  const float* conv3m_b= (const float*)d_in[36];
  const float* conv2m_w= (const float*)d_in[37];
  const float* conv2m_b= (const float*)d_in[38];
  const float* conv1m_w= (const float*)d_in[39];
  const float* conv1m_b= (const float*)d_in[40];

  float* ws = (float*)d_ws;

  // lifetime-packed arena (floats), stats in [0,1024). Extents:
  //  p1  [0, 3211264)           live [2..4]
  //  a1  [3211264, 16056320)    live [1..2]
  //  om2 [3211264, 4566016)     live [3..4]
  //  a2  [4566016, 10988544)    live [4..6]
  //  a3  [10988544, 17411072)   live [6..7]
  //  p2  [0, 1605632)           live [7..9]
  //  om41[1605632, 1944320)     live [8..9]
  //  a41 [1944320, 2747136)     live [9..11]
  //  a4  [2747136, 2772224)     live [11..12]
  //  t4m [2772224, 8310016)     live [12..13]
  //  t3m [8310016, 11996416)    live [13..14]
  //  t2m [11996416, 18885888)   live [14..15]
  //  t1m [0, 401408)            live [15..16]
  //  wT2 [17411072, 17484800)   live [0..4]  -- only t2m (step 14) touches this range
  //  wT41[17484800, 17558528)   live [0..9]  -- only t2m (step 14) touches this range
  const long long AB = 1024;
  float* p1   = ws + AB;
  float* a1   = ws + AB + 3211264;
  float* om2  = ws + AB + 3211264;
  float* a2   = ws + AB + 4566016;
  float* a3   = ws + AB + 10988544;
  float* p2   = ws + AB;
  float* om41 = ws + AB + 1605632;
  float* a41  = ws + AB + 1944320;
  float* a4   = ws + AB + 2747136;
  float* t4m  = ws + AB + 2772224;
  float* t3m  = ws + AB + 8310016;
  float* t2m  = ws + AB + 11996416;
  float* t1m  = ws + AB;
  float* wT2  = ws + AB + 17411072;
  float* wT41 = ws + AB + 17484800;

  float* s1  = ws + 0;   float* q1  = ws + 64;
  float* s2  = ws + 128; float* q2  = ws + 256;
  float* s3  = ws + 384; float* q3  = ws + 512;
  float* s41 = ws + 640; float* q41 = ws + 704;

  auto nb = [](long long n){ return (int)((n + 255)/256); };

  hipMemsetAsync(d_ws, 0, 4096, stream);

  // weight pre-transposes for deform GEMMs (coalesced lane-o reads)
  wtrans_kernel<<<nb(73728), 256, 0, stream>>>(dc2_w,  wT2,  64, 128);
  wtrans_kernel<<<nb(73728), 256, 0, stream>>>(dc41_w, wT41, 128, 64);

  // [1] conv1 (2->64, 28x28), fused bn1 stats
  conv1_tiled<<<dim3(B,8), 256, 0, stream>>>(x1, conv1_w, conv1_b, a1, s1, q1);
  // [2] bn1 + elu + avgpool -> p1
  bn_elu_pool_kernel<<<nb((long long)B*64*196), 256, 0, stream>>>(a1, bn1_g, bn1_b, s1, q1, p1,
                                                                  B, 64, 28, 28, 1.f/200704.f);
  // [3] dc2 offsets (64->18) + mask (64->9, sigmoid) -> om2
  conv_tiled_cs<14,14,14,14,1,false,8><<<dim3(B,2), 256, 0, stream>>>(p1, dc2_pw, dc2_pb, om2,
                                                                      nullptr, nullptr, 64, 18, 0, 27, 0, 0);
  conv_tiled_cs<14,14,14,14,1,false,8><<<dim3(B,1), 256, 0, stream>>>(p1, dc2_mw, dc2_mb, om2,
                                                                      nullptr, nullptr, 64, 9, 0, 27, 18, 1);
  // [4] deform conv 2 (64->128) -> a2, fused bn2 stats
  deform_gemm<64,128,14,14,49,2><<<B*4, 256, 0, stream>>>(p1, om2, wT2, a2, s2, q2);
  // [5] bn2 + elu
  bn_elu_inplace_kernel<<<nb((long long)B*128*196), 256, 0, stream>>>(a2, bn2_g, bn2_b, s2, q2,
                                                                      128, 196, 1.f/50176.f, B*128*196);
  // [6] conv3 (128->128) -> a3, fused bn3 stats
  conv_tiled_cs<14,14,14,14,1,false,8><<<dim3(B,8), 256, 0, stream>>>(a2, conv3_w, conv3_b, a3,
                                                                      s3, q3, 128, 128, 0, 128, 0, 0);
  // [7] bn3 + elu + avgpool -> p2
  bn_elu_pool_kernel<<<nb((long long)B*128*49), 256, 0, stream>>>(a3, bn3_g, bn3_b, s3, q3, p2,
                                                                  B, 128, 14, 14, 1.f/50176.f);
  // [8] dc41 offsets + mask -> om41
  conv_tiled_cs<7,7,7,7,1,false,8><<<dim3(B,2), 256, 0, stream>>>(p2, dc41_pw, dc41_pb, om41,
                                                                  nullptr, nullptr, 128, 18, 0, 27, 0, 0);
  conv_tiled_cs<7,7,7,7,1,false,8><<<dim3(B,1), 256, 0, stream>>>(p2, dc41_mw, dc41_mb, om41,
                                                                  nullptr, nullptr, 128, 9, 0, 27, 18, 1);
  // [9] deform conv 41 (128->64) -> a41, fused bn41 stats
  deform_gemm<128,64,7,7,13,4><<<B*4, 256, 0, stream>>>(p2, om41, wT41, a41, s41, q41);
  // [10] bn41 + elu
  bn_elu_inplace_kernel<<<nb((long long)B*64*49), 256, 0, stream>>>(a41, bn41_g, bn41_b, s41, q41,
                                                                    64, 49, 1.f/12544.f, B*64*49);
  // [11] conv4 (64->2, 7x7) naive (tiny)
  conv3x3_kernel<<<nb((long long)B*2*49), 256, 0, stream>>>(a41, conv4_w, conv4_b, a4,
                                                            B, 64, 2, 7, 7, 2, 0, 0);
  // [12] convT4m: 2->128, s=2, p=1, 7->13, parity-decomposed
  convt_s2_tiled<7,7,2,128,false><<<dim3(B,8), 256, 0, stream>>>(a4, conv4m_w, conv4m_b, t4m);
  // [13] convT3m: 128->64, s=1 == conv pad2 flipped, +elu
  conv_tiled_cs<13,13,15,15,2,true,8><<<dim3(B,4), 256, 0, stream>>>(t4m, conv3m_w, conv3m_b, t3m,
                                                                     nullptr, nullptr, 128, 64, 64, 64, 0, 2);
  // [14] convT2m: 64->32, s=2, p=1, 15->29, +elu, parity-decomposed
  convt_s2_tiled<15,15,64,32,true><<<dim3(B,2), 256, 0, stream>>>(t3m, conv2m_w, conv2m_b, t2m);
  // [15] convT1m: 32->2, k=2, s=1, p=1, 29->28, +elu (naive, tiny)
  convt_kernel<<<nb((long long)B*2*784), 256, 0, stream>>>(t2m, conv1m_w, conv1m_b, t1m,
                                                           B, 32, 2, 29, 29, 28, 28, 2, 1, 0, 1);
  // [16] final warp
  warp_kernel<<<nb((long long)B*784), 256, 0, stream>>>(t1m, x1, (float*)d_out, B);
}

// Round 8
// 1801.509 us; speedup vs baseline: 4.6943x; 1.0389x over previous
//
#include <hip/hip_runtime.h>
#include <hip/hip_bf16.h>

__device__ __forceinline__ float eluf(float x){ return x > 0.f ? x : expm1f(x); }

// ---------------- naive 3x3 pad-1 conv (kept only for tiny conv4) ----------------
__global__ void conv3x3_kernel(const float* __restrict__ in, const float* __restrict__ w,
                               const float* __restrict__ bias, float* __restrict__ out,
                               int B, int Cin, int Cout, int H, int W, int Ctot, int ooff, int act)
{
  int idx = blockIdx.x*256 + threadIdx.x;
  int total = B*Cout*H*W;
  if (idx >= total) return;
  int x = idx % W; int t = idx / W;
  int y = t % H;   t /= H;
  int o = t % Cout; int b = t / Cout;
  float acc = bias ? bias[o] : 0.f;
  const float* wp = w + (long long)o*Cin*9;
  for (int c = 0; c < Cin; c++){
    const float* ip = in + (long long)(b*Cin + c)*H*W;
    const float* wc = wp + c*9;
    #pragma unroll
    for (int ky = 0; ky < 3; ky++){
      int iy = y + ky - 1; if ((unsigned)iy >= (unsigned)H) continue;
      #pragma unroll
      for (int kx = 0; kx < 3; kx++){
        int ix = x + kx - 1; if ((unsigned)ix >= (unsigned)W) continue;
        acc += wc[ky*3+kx] * ip[iy*W + ix];
      }
    }
  }
  if (act == 1) acc = 1.f/(1.f + expf(-acc));
  out[(((long long)b*Ctot + ooff + o)*H + y)*W + x] = acc;
}

// ---------------- conv1: 2->64, 28x28, fused bn-stats ----------------
__global__ __launch_bounds__(256)
void conv1_tiled(const float* __restrict__ in, const float* __restrict__ w,
                 const float* __restrict__ bias, float* __restrict__ out,
                 float* __restrict__ sum, float* __restrict__ sq)
{
  __shared__ float img[2][30*31];
  __shared__ float wl[2][8*9];
  const int b = blockIdx.x, o0 = blockIdx.y*8, t = threadIdx.x;
  const int ol = t >> 5, y = t & 31;
  for (int idx = t; idx < 2*930; idx += 256) ((float*)img)[idx] = 0.f;
  __syncthreads();
  for (int idx = t; idx < 2*784; idx += 256){
    int cl = idx/784, r = idx%784;
    img[cl][(r/28 + 1)*31 + (r%28) + 1] = in[((long long)b*2)*784 + idx];
  }
  if (t < 144){
    int cl = t/72, r = t%72;
    wl[cl][r] = w[(((long long)(o0 + r/9))*2 + cl)*9 + (r%9)];
  }
  __syncthreads();
  const bool active = (y < 28);
  float acc[28];
  #pragma unroll
  for (int x = 0; x < 28; x++) acc[x] = 0.f;
  if (active){
    for (int cl = 0; cl < 2; cl++){
      #pragma unroll
      for (int ky = 0; ky < 3; ky++){
        const float* row = &img[cl][(y+ky)*31];
        float rin[30];
        #pragma unroll
        for (int x = 0; x < 30; x++) rin[x] = row[x];
        #pragma unroll
        for (int kx = 0; kx < 3; kx++){
          float wv = wl[cl][ol*9 + ky*3 + kx];
          #pragma unroll
          for (int x = 0; x < 28; x++) acc[x] += wv * rin[x+kx];
        }
      }
    }
  }
  const int og = o0 + ol;
  float sv = 0.f, qv = 0.f;
  if (active){
    float bv = bias[og];
    float* po = out + (((long long)b*64 + og)*28 + y)*28;
    #pragma unroll
    for (int x = 0; x < 28; x++){
      float v = acc[x] + bv;
      po[x] = v;
      sv += v; qv += v*v;
    }
  }
  #pragma unroll
  for (int d = 16; d > 0; d >>= 1){
    sv += __shfl_down(sv, d, 32);
    qv += __shfl_down(qv, d, 32);
  }
  if (y == 0){ atomicAdd(&sum[og], sv); atomicAdd(&sq[og], qv); }
}

// ---------------- tiled 3x3 conv, CS=1, 16-o tile (for small Cout convs) ----------------
template<int HIN,int WIN,int HOUT,int WOUT,int PAD>
__global__ __launch_bounds__(256)
void conv_tiled(const float* __restrict__ in, const float* __restrict__ w,
                const float* __restrict__ bias, float* __restrict__ out,
                int Cin, int Cout, int Ctot, int ooff, int act)
{
  constexpr int HP = HIN + 2*PAD, WP = WIN + 2*PAD, WPL = WP + 1;
  __shared__ float img[HP*WPL];
  __shared__ float wl[16*9];
  const int b  = blockIdx.x;
  const int o0 = blockIdx.y * 16;
  const int t  = threadIdx.x;
  const int ol = t >> 4, y = t & 15;
  const bool act_th = (y < HOUT) && (o0 + ol < Cout);
  float acc[WOUT];
  #pragma unroll
  for (int x = 0; x < WOUT; x++) acc[x] = 0.f;
  for (int idx = t; idx < HP*WPL; idx += 256) img[idx] = 0.f;
  const long long inb = (long long)b*Cin*HIN*WIN;
  for (int c = 0; c < Cin; c++){
    __syncthreads();
    for (int idx = t; idx < HIN*WIN; idx += 256){
      int iy = idx / WIN, ix = idx % WIN;
      img[(iy+PAD)*WPL + (ix+PAD)] = in[inb + (long long)c*HIN*WIN + idx];
    }
    if (t < 144){
      int oo = t / 9, kk = t % 9;
      int og = o0 + oo;
      wl[t] = (og < Cout) ? w[((long long)og*Cin + c)*9 + kk] : 0.f;
    }
    __syncthreads();
    if (act_th){
      #pragma unroll
      for (int ky = 0; ky < 3; ky++){
        const float* row = &img[(y+ky)*WPL];
        float rin[WOUT+2];
        #pragma unroll
        for (int x = 0; x < WOUT+2; x++) rin[x] = row[x];
        #pragma unroll
        for (int kx = 0; kx < 3; kx++){
          float wv = wl[ol*9 + ky*3 + kx];
          #pragma unroll
          for (int x = 0; x < WOUT; x++) acc[x] += wv * rin[x+kx];
        }
      }
    }
  }
  if (act_th){
    int og = o0 + ol;
    float bv = bias[og];
    #pragma unroll
    for (int x = 0; x < WOUT; x++){
      float v = acc[x] + bv;
      if (act == 1) v = 1.f/(1.f + expf(-v));
      else if (act == 2) v = eluf(v);
      out[(((long long)b*Ctot + ooff + og)*HOUT + y)*WOUT + x] = v;
    }
  }
}

// ---------------- tiled 3x3 conv, CS=1, 32-o tile (2 o's per thread) ----------------
// TRANSP: weight (Cin, CoutW, 3,3) flipped. Optional fused stats. act: 0 none, 2 elu.
template<int HIN,int WIN,int HOUT,int WOUT,int PAD,bool TRANSP>
__global__ __launch_bounds__(256)
void conv_tiled_w2(const float* __restrict__ in, const float* __restrict__ w,
                   const float* __restrict__ bias, float* __restrict__ out,
                   float* __restrict__ sum, float* __restrict__ sq,
                   int Cin, int Cout, int CoutW, int act)
{
  constexpr int HP = HIN + 2*PAD, WP = WIN + 2*PAD, WPL = WP + 1;
  __shared__ float img[HP*WPL];
  __shared__ float wl[32*9];
  const int b  = blockIdx.x;
  const int o0 = blockIdx.y * 32;
  const int t  = threadIdx.x;
  const int ol = t >> 4, y = t & 15;
  const bool act_th = (y < HOUT);
  float acc0[WOUT], acc1[WOUT];
  #pragma unroll
  for (int x = 0; x < WOUT; x++){ acc0[x] = 0.f; acc1[x] = 0.f; }
  for (int idx = t; idx < HP*WPL; idx += 256) img[idx] = 0.f;
  const long long inb = (long long)b*Cin*HIN*WIN;
  for (int c = 0; c < Cin; c++){
    __syncthreads();
    for (int idx = t; idx < HIN*WIN; idx += 256){
      int iy = idx / WIN, ix = idx % WIN;
      img[(iy+PAD)*WPL + (ix+PAD)] = in[inb + (long long)c*HIN*WIN + idx];
    }
    for (int idx = t; idx < 288; idx += 256){
      int oo = idx / 9, kk = idx % 9;
      int og = o0 + oo;
      float wv;
      if (TRANSP) wv = w[((long long)c*CoutW + og)*9 + (2 - kk/3)*3 + (2 - kk%3)];
      else        wv = w[((long long)og*Cin + c)*9 + kk];
      wl[idx] = wv;
    }
    __syncthreads();
    if (act_th){
      #pragma unroll
      for (int ky = 0; ky < 3; ky++){
        const float* row = &img[(y+ky)*WPL];
        float rin[WOUT+2];
        #pragma unroll
        for (int x = 0; x < WOUT+2; x++) rin[x] = row[x];
        #pragma unroll
        for (int kx = 0; kx < 3; kx++){
          float wv0 = wl[ol*9 + ky*3 + kx];
          float wv1 = wl[(ol+16)*9 + ky*3 + kx];
          #pragma unroll
          for (int x = 0; x < WOUT; x++){
            acc0[x] += wv0 * rin[x+kx];
            acc1[x] += wv1 * rin[x+kx];
          }
        }
      }
    }
  }
  const int og0 = o0 + ol, og1 = o0 + ol + 16;
  float sv0 = 0.f, qv0 = 0.f, sv1 = 0.f, qv1 = 0.f;
  if (act_th){
    float bv0 = bias[og0], bv1 = bias[og1];
    float* po0 = out + (((long long)b*Cout + og0)*HOUT + y)*WOUT;
    float* po1 = out + (((long long)b*Cout + og1)*HOUT + y)*WOUT;
    #pragma unroll
    for (int x = 0; x < WOUT; x++){
      float v0 = acc0[x] + bv0;
      float v1 = acc1[x] + bv1;
      po0[x] = (act == 2) ? eluf(v0) : v0;
      po1[x] = (act == 2) ? eluf(v1) : v1;
      sv0 += v0; qv0 += v0*v0; sv1 += v1; qv1 += v1*v1;
    }
  }
  if (sum){
    #pragma unroll
    for (int d = 8; d > 0; d >>= 1){
      sv0 += __shfl_down(sv0, d, 16); qv0 += __shfl_down(qv0, d, 16);
      sv1 += __shfl_down(sv1, d, 16); qv1 += __shfl_down(qv1, d, 16);
    }
    if (y == 0){
      atomicAdd(&sum[og0], sv0); atomicAdd(&sq[og0], qv0);
      atomicAdd(&sum[og1], sv1); atomicAdd(&sq[og1], qv1);
    }
  }
}

// ---------------- stride-2 transpose conv, parity-decomposed ----------------
template<int HIN,int WIN,int CIN,int COUT,bool DO_ELU>
__global__ __launch_bounds__(256)
void convt_s2_tiled(const float* __restrict__ in, const float* __restrict__ w,
                    const float* __restrict__ bias, float* __restrict__ out)
{
  constexpr int HOUT = 2*HIN - 1, WOUT = 2*WIN - 1;
  __shared__ float img[17*16];
  __shared__ float wl[16][10];
  const int b  = blockIdx.x;
  const int o0 = blockIdx.y * 16;
  const int t  = threadIdx.x;
  const int ol = t >> 4, yb = t & 15;
  for (int idx = t; idx < 17*16; idx += 256) img[idx] = 0.f;
  float accA[WOUT], accB[WOUT];
  #pragma unroll
  for (int x = 0; x < WOUT; x++){ accA[x] = 0.f; accB[x] = 0.f; }
  for (int c = 0; c < CIN; c++){
    __syncthreads();
    for (int idx = t; idx < HIN*WIN; idx += 256)
      img[(idx/WIN)*16 + idx%WIN] = in[((long long)b*CIN + c)*HIN*WIN + idx];
    if (t < 144)
      wl[t/9][t%9] = w[(((long long)c*COUT + o0 + t/9)*3 + (t%9)/3)*3 + (t%9)%3];
    __syncthreads();
    float ru[16], rd[16];
    #pragma unroll
    for (int q = 0; q < 4; q++){
      float4 va = ((const float4*)&img[yb*16])[q];
      ru[4*q+0]=va.x; ru[4*q+1]=va.y; ru[4*q+2]=va.z; ru[4*q+3]=va.w;
      float4 vb = ((const float4*)&img[(yb+1)*16])[q];
      rd[4*q+0]=vb.x; rd[4*q+1]=vb.y; rd[4*q+2]=vb.z; rd[4*q+3]=vb.w;
    }
    float w00=wl[ol][0], w01=wl[ol][1], w02=wl[ol][2];
    float w10=wl[ol][3], w11=wl[ol][4], w12=wl[ol][5];
    float w20=wl[ol][6], w21=wl[ol][7], w22=wl[ol][8];
    #pragma unroll
    for (int v = 0; v < WIN; v++){
      accA[2*v] += w11*ru[v];
      accB[2*v] += w21*ru[v] + w01*rd[v];
    }
    #pragma unroll
    for (int v = 0; v < WIN-1; v++){
      accA[2*v+1] += w12*ru[v] + w10*ru[v+1];
      accB[2*v+1] += w22*ru[v] + w20*ru[v+1] + w02*rd[v] + w00*rd[v+1];
    }
  }
  const int og = o0 + ol;
  const float bv = bias[og];
  const int yA = 2*yb, yB = 2*yb + 1;
  if (yA < HOUT){
    float* po = out + (((long long)b*COUT + og)*HOUT + yA)*WOUT;
    #pragma unroll
    for (int x = 0; x < WOUT; x++){ float v = accA[x] + bv; po[x] = DO_ELU ? eluf(v) : v; }
  }
  if (yB < HOUT){
    float* po = out + (((long long)b*COUT + og)*HOUT + yB)*WOUT;
    #pragma unroll
    for (int x = 0; x < WOUT; x++){ float v = accB[x] + bv; po[x] = DO_ELU ? eluf(v) : v; }
  }
}

// ---------------- deform weight transpose: w[o][c][kk] -> wT[cc][cl*9+kk][o] ----------------
__global__ void wtrans_kernel(const float* __restrict__ w, float* __restrict__ wT,
                              int CIN, int COUT)
{
  int n = CIN*COUT*9;
  int idx = blockIdx.x*256 + threadIdx.x;
  if (idx >= n) return;
  int cc = idx / (72*COUT);
  int r  = idx % (72*COUT);
  int k  = r / COUT, o = r % COUT;
  int c  = cc*8 + k/9, kk = k%9;
  wT[idx] = w[((long long)o*CIN + c)*9 + kk];
}

// ---------------- deformable conv, fused gather-GEMM, transposed weights, fused stats ----------------
template<int CIN,int COUT,int H,int W,int PXT,int PXG>
__global__ __launch_bounds__(256)
void deform_gemm(const float* __restrict__ x, const float* __restrict__ om,
                 const float* __restrict__ wT, float* __restrict__ out,
                 float* __restrict__ sum, float* __restrict__ sq)
{
  constexpr int HW = H*W;
  constexpr int NT = (HW + PXT - 1)/PXT;
  constexpr int PPT = (PXT + PXG - 1)/PXG;
  constexpr int PXTP = PPT*PXG;
  __shared__ float simg[8*HW];
  __shared__ float S[72*PXTP];
  __shared__ float kwv[PXT*9*4];
  __shared__ int   kidx[PXT*9*4];
  __shared__ float red[512];
  const int tile = blockIdx.x % NT;
  const int b    = blockIdx.x / NT;
  const int t    = threadIdx.x;
  const int o    = t % COUT;
  const int pxg  = t / COUT;
  const int Hp = H + 2, Wp = W + 2;
  for (int it = t; it < PXT*9; it += 256){
    int px = it / 9, kk = it % 9;
    int p = tile*PXT + px;
    float w0=0.f,w1=0.f,w2=0.f,w3=0.f;
    int i0=0,i1=0,i2=0,i3=0;
    if (p < HW){
      int i = p / W, j = p % W;
      long long base = ((long long)b*27)*HW + p;
      float offx = om[base + (long long)kk*HW];
      float offy = om[base + (long long)(9+kk)*HW];
      float mk   = om[base + (long long)(18+kk)*HW];
      float pnx = (float)(kk/3) - 1.f;
      float pny = (float)(kk%3) - 1.f;
      float px_ = fminf(fmaxf((float)(i+1) + pnx + offx, 0.f), (float)(Hp-1));
      float py_ = fminf(fmaxf((float)(j+1) + pny + offy, 0.f), (float)(Wp-1));
      float fx = floorf(px_), fy = floorf(py_);
      float x0 = fmaxf(fx, 0.f), y0 = fmaxf(fy, 0.f);
      float x1c = fminf(fx + 1.f, (float)(Hp-1));
      float y1c = fminf(fy + 1.f, (float)(Wp-1));
      float glt = (1.f + (x0 - px_)) * (1.f + (y0 - py_));
      float grb = (1.f - (x1c - px_)) * (1.f - (y1c - py_));
      float glb = (1.f + (x0 - px_)) * (1.f - (y1c - py_));
      float grt = (1.f - (x1c - px_)) * (1.f + (y0 - py_));
      int ax0=(int)x0, ay0=(int)y0, ax1=(int)x1c, ay1=(int)y1c;
      if (ax0>=1 && ax0<=H && ay0>=1 && ay0<=W){ w0 = glt*mk; i0 = (ax0-1)*W + (ay0-1); }
      if (ax1>=1 && ax1<=H && ay1>=1 && ay1<=W){ w1 = grb*mk; i1 = (ax1-1)*W + (ay1-1); }
      if (ax0>=1 && ax0<=H && ay1>=1 && ay1<=W){ w2 = glb*mk; i2 = (ax0-1)*W + (ay1-1); }
      if (ax1>=1 && ax1<=H && ay0>=1 && ay0<=W){ w3 = grt*mk; i3 = (ax1-1)*W + (ay0-1); }
    }
    int b4 = it*4;
    kwv[b4+0]=w0; kwv[b4+1]=w1; kwv[b4+2]=w2; kwv[b4+3]=w3;
    kidx[b4+0]=i0; kidx[b4+1]=i1; kidx[b4+2]=i2; kidx[b4+3]=i3;
  }
  float acc[PPT];
  #pragma unroll
  for (int pp = 0; pp < PPT; pp++) acc[pp] = 0.f;
  for (int cc = 0; cc < CIN/8; cc++){
    __syncthreads();
    for (int idx = t; idx < 8*HW; idx += 256)
      simg[idx] = x[((long long)b*CIN + cc*8)*HW + idx];
    __syncthreads();
    for (int idx = t; idx < 72*PXT; idx += 256){
      int k = idx / PXT, px = idx % PXT;
      int b4 = (px*9 + (k%9))*4;
      const float* im = &simg[(k/9)*HW];
      float v = kwv[b4+0]*im[kidx[b4+0]] + kwv[b4+1]*im[kidx[b4+1]]
              + kwv[b4+2]*im[kidx[b4+2]] + kwv[b4+3]*im[kidx[b4+3]];
      S[k*PXTP + px] = v;
    }
    __syncthreads();
    const float* wc = wT + (long long)cc*72*COUT;
    #pragma unroll 4
    for (int k = 0; k < 72; k++){
      float wv = wc[k*COUT + o];
      #pragma unroll
      for (int pp = 0; pp < PPT; pp++)
        acc[pp] += wv * S[k*PXTP + pxg*PPT + pp];
    }
  }
  float sv = 0.f, qv = 0.f;
  #pragma unroll
  for (int pp = 0; pp < PPT; pp++){
    int pxl = pxg*PPT + pp;
    int p = tile*PXT + pxl;
    if (pxl < PXT && p < HW){
      out[((long long)b*COUT + o)*HW + p] = acc[pp];
      sv += acc[pp]; qv += acc[pp]*acc[pp];
    }
  }
  red[t] = sv; red[256 + t] = qv;
  __syncthreads();
  if (t < COUT){
    float S2 = 0.f, Q2 = 0.f;
    #pragma unroll
    for (int g = 0; g < PXG; g++){ S2 += red[g*COUT + t]; Q2 += red[256 + g*COUT + t]; }
    atomicAdd(&sum[t], S2); atomicAdd(&sq[t], Q2);
  }
}

// ---------------- bn + elu + 2x2 avgpool ----------------
__global__ void bn_elu_pool_kernel(const float* __restrict__ in, const float* __restrict__ g,
                                   const float* __restrict__ bb, const float* __restrict__ sum,
                                   const float* __restrict__ sq, float* __restrict__ out,
                                   int B, int C, int H, int W, float invN)
{
  int Ho = H/2, Wo = W/2;
  int idx = blockIdx.x*256 + threadIdx.x;
  int total = B*C*Ho*Wo;
  if (idx >= total) return;
  int x = idx % Wo; int t = idx / Wo;
  int y = t % Ho;   t /= Ho;
  int c = t % C;    int b = t / C;
  float mean = sum[c]*invN;
  float var  = sq[c]*invN - mean*mean;
  float sc = g[c] * rsqrtf(var + 1e-5f);
  float sh = bb[c] - mean*sc;
  const float* p = in + (long long)(b*C + c)*H*W;
  float acc = 0.f;
  #pragma unroll
  for (int dy = 0; dy < 2; dy++)
    #pragma unroll
    for (int dx = 0; dx < 2; dx++)
      acc += eluf(sc*p[(2*y+dy)*W + (2*x+dx)] + sh);
  out[idx] = acc * 0.25f;
}

// ---------------- bn + elu in place ----------------
__global__ void bn_elu_inplace_kernel(float* __restrict__ xio, const float* __restrict__ g,
                                      const float* __restrict__ bb, const float* __restrict__ sum,
                                      const float* __restrict__ sq, int C, int HW, float invN, int total)
{
  int idx = blockIdx.x*256 + threadIdx.x;
  if (idx >= total) return;
  int c = (idx / HW) % C;
  float mean = sum[c]*invN;
  float var  = sq[c]*invN - mean*mean;
  float sc = g[c] * rsqrtf(var + 1e-5f);
  float sh = bb[c] - mean*sc;
  xio[idx] = eluf(sc*xio[idx] + sh);
}

// ---------------- generic transpose conv (kept for convT1m) ----------------
__global__ void convt_kernel(const float* __restrict__ in, const float* __restrict__ w,
                             const float* __restrict__ bias, float* __restrict__ out,
                             int B, int Cin, int Cout, int Hin, int Win, int Hout, int Wout,
                             int K, int S, int PP, int do_elu)
{
  int idx = blockIdx.x*256 + threadIdx.x;
  int total = B*Cout*Hout*Wout;
  if (idx >= total) return;
  int x = idx % Wout; int t = idx / Wout;
  int y = t % Hout;   t /= Hout;
  int o = t % Cout;   int b = t / Cout;
  float acc = bias[o];
  for (int ky = 0; ky < K; ky++){
    int dy = y + ky - PP;
    if (dy < 0 || (dy % S) != 0) continue;
    int iy = dy / S; if (iy >= Hin) continue;
    int wky = K - 1 - ky;
    for (int kx = 0; kx < K; kx++){
      int dx = x + kx - PP;
      if (dx < 0 || (dx % S) != 0) continue;
      int ix = dx / S; if (ix >= Win) continue;
      int wkx = K - 1 - kx;
      const float* ip = in + (long long)b*Cin*Hin*Win + (long long)iy*Win + ix;
      for (int c = 0; c < Cin; c++){
        acc += w[(((long long)c*Cout + o)*K + wky)*K + wkx] * ip[(long long)c*Hin*Win];
      }
    }
  }
  if (do_elu) acc = eluf(acc);
  out[idx] = acc;
}

// ---------------- final bicubic warp ----------------
__device__ __forceinline__ float cubicf(float A, float Bv, float C, float D, float t){
  float a = -0.5f*A + 1.5f*Bv - 1.5f*C + 0.5f*D;
  float b =  A - 2.5f*Bv + 2.0f*C - 0.5f*D;
  float c = -0.5f*A + 0.5f*C;
  return ((a*t + b)*t + c)*t + Bv;
}

__global__ void warp_kernel(const float* __restrict__ V, const float* __restrict__ x1,
                            float* __restrict__ out, int B)
{
  int idx = blockIdx.x*256 + threadIdx.x;
  int total = B*784;
  if (idx >= total) return;
  int j = idx % 28; int t = idx / 28;
  int i = t % 28;   int b = t / 28;
  float v0 = V[((long long)b*2 + 0)*784 + j*28 + i];
  float v1 = V[((long long)b*2 + 1)*784 + j*28 + i];
  float gx = (-1.f + 2.f*(float)j/27.f) + v0;
  float gy = (-1.f + 2.f*(float)i/27.f) + v1;
  float ix = (gx + 1.f)*13.5f;
  float iy = (gy + 1.f)*13.5f;
  float x0 = floorf(ix), y0 = floorf(iy);
  float tx = ix - x0, ty = iy - y0;
  const float* img = x1 + (long long)b*2*784;
  float rows[4];
  #pragma unroll
  for (int ky = -1; ky <= 2; ky++){
    int yi = (int)fminf(fmaxf(y0 + (float)ky, 0.f), 27.f);
    float cv[4];
    #pragma unroll
    for (int kx = -1; kx <= 2; kx++){
      int xi = (int)fminf(fmaxf(x0 + (float)kx, 0.f), 27.f);
      cv[kx+1] = img[yi*28 + xi];
    }
    rows[ky+1] = cubicf(cv[0], cv[1], cv[2], cv[3], tx);
  }
  out[idx] = cubicf(rows[0], rows[1], rows[2], rows[3], ty);
}

// ---------------- host ----------------
extern "C" void kernel_launch(void* const* d_in, const int* in_sizes, int n_in,
                              void* d_out, int out_size, void* d_ws, size_t ws_size,
                              hipStream_t stream)
{
  const int B = 256;
  const float* x1      = (const float*)d_in[0];
  const float* conv1_w = (const float*)d_in[9];
  const float* conv1_b = (const float*)d_in[10];
  const float* bn1_g   = (const float*)d_in[11];
  const float* bn1_b   = (const float*)d_in[12];
  const float* dc2_pw  = (const float*)d_in[13];
  const float* dc2_pb  = (const float*)d_in[14];
  const float* dc2_mw  = (const float*)d_in[15];
  const float* dc2_mb  = (const float*)d_in[16];
  const float* dc2_w   = (const float*)d_in[17];
  const float* bn2_g   = (const float*)d_in[18];
  const float* bn2_b   = (const float*)d_in[19];
  const float* conv3_w = (const float*)d_in[20];
  const float* conv3_b = (const float*)d_in[21];
  const float* bn3_g   = (const float*)d_in[22];
  const float* bn3_b   = (const float*)d_in[23];
  const float* dc41_pw = (const float*)d_in[24];
  const float* dc41_pb = (const float*)d_in[25];
  const float* dc41_mw = (const float*)d_in[26];
  const float* dc41_mb = (const float*)d_in[27];
  const float* dc41_w  = (const float*)d_in[28];
  const float* bn41_g  = (const float*)d_in[29];
  const float* bn41_b  = (const float*)d_in[30];
  const float* conv4_w = (const float*)d_in[31];
  const float* conv4_b = (const float*)d_in[32];
  const float* conv4m_w= (const float*)d_in[33];
  const float* conv4m_b= (const float*)d_in[34];
  const float* conv3m_w= (const float*)d_in[35];
  const float* conv3m_b= (const float*)d_in[36];
  const float* conv2m_w= (const float*)d_in[37];
  const float* conv2m_b= (const float*)d_in[38];
  const float* conv1m_w= (const float*)d_in[39];
  const float* conv1m_b= (const float*)d_in[40];

  float* ws = (float*)d_ws;

  // lifetime-packed arena (floats), stats in [0,1024). (layout identical to R7 — verified)
  const long long AB = 1024;
  float* p1   = ws + AB;
  float* a1   = ws + AB + 3211264;
  float* om2  = ws + AB + 3211264;
  float* a2   = ws + AB + 4566016;
  float* a3   = ws + AB + 10988544;
  float* p2   = ws + AB;
  float* om41 = ws + AB + 1605632;
  float* a41  = ws + AB + 1944320;
  float* a4   = ws + AB + 2747136;
  float* t4m  = ws + AB + 2772224;
  float* t3m  = ws + AB + 8310016;
  float* t2m  = ws + AB + 11996416;
  float* t1m  = ws + AB;
  float* wT2  = ws + AB + 17411072;
  float* wT41 = ws + AB + 17484800;

  float* s1  = ws + 0;   float* q1  = ws + 64;
  float* s2  = ws + 128; float* q2  = ws + 256;
  float* s3  = ws + 384; float* q3  = ws + 512;
  float* s41 = ws + 640; float* q41 = ws + 704;

  auto nb = [](long long n){ return (int)((n + 255)/256); };

  hipMemsetAsync(d_ws, 0, 4096, stream);

  // weight pre-transposes for deform GEMMs
  wtrans_kernel<<<nb(73728), 256, 0, stream>>>(dc2_w,  wT2,  64, 128);
  wtrans_kernel<<<nb(73728), 256, 0, stream>>>(dc41_w, wT41, 128, 64);

  // [1] conv1 (2->64, 28x28), fused bn1 stats
  conv1_tiled<<<dim3(B,8), 256, 0, stream>>>(x1, conv1_w, conv1_b, a1, s1, q1);
  // [2] bn1 + elu + avgpool -> p1
  bn_elu_pool_kernel<<<nb((long long)B*64*196), 256, 0, stream>>>(a1, bn1_g, bn1_b, s1, q1, p1,
                                                                  B, 64, 28, 28, 1.f/200704.f);
  // [3] dc2 offsets (64->18) + mask (64->9, sigmoid) -> om2 (CS=1 proven shape)
  conv_tiled<14,14,14,14,1><<<dim3(B,2), 256, 0, stream>>>(p1, dc2_pw, dc2_pb, om2,
                                                           64, 18, 27, 0, 0);
  conv_tiled<14,14,14,14,1><<<dim3(B,1), 256, 0, stream>>>(p1, dc2_mw, dc2_mb, om2,
                                                           64, 9, 27, 18, 1);
  // [4] deform conv 2 (64->128) -> a2, fused bn2 stats
  deform_gemm<64,128,14,14,49,2><<<B*4, 256, 0, stream>>>(p1, om2, wT2, a2, s2, q2);
  // [5] bn2 + elu
  bn_elu_inplace_kernel<<<nb((long long)B*128*196), 256, 0, stream>>>(a2, bn2_g, bn2_b, s2, q2,
                                                                      128, 196, 1.f/50176.f, B*128*196);
  // [6] conv3 (128->128) -> a3, 32-o tile, fused bn3 stats
  conv_tiled_w2<14,14,14,14,1,false><<<dim3(B,4), 256, 0, stream>>>(a2, conv3_w, conv3_b, a3,
                                                                    s3, q3, 128, 128, 0, 0);
  // [7] bn3 + elu + avgpool -> p2
  bn_elu_pool_kernel<<<nb((long long)B*128*49), 256, 0, stream>>>(a3, bn3_g, bn3_b, s3, q3, p2,
                                                                  B, 128, 14, 14, 1.f/50176.f);
  // [8] dc41 offsets + mask -> om41
  conv_tiled<7,7,7,7,1><<<dim3(B,2), 256, 0, stream>>>(p2, dc41_pw, dc41_pb, om41,
                                                       128, 18, 27, 0, 0);
  conv_tiled<7,7,7,7,1><<<dim3(B,1), 256, 0, stream>>>(p2, dc41_mw, dc41_mb, om41,
                                                       128, 9, 27, 18, 1);
  // [9] deform conv 41 (128->64) -> a41, fused bn41 stats
  deform_gemm<128,64,7,7,13,4><<<B*4, 256, 0, stream>>>(p2, om41, wT41, a41, s41, q41);
  // [10] bn41 + elu
  bn_elu_inplace_kernel<<<nb((long long)B*64*49), 256, 0, stream>>>(a41, bn41_g, bn41_b, s41, q41,
                                                                    64, 49, 1.f/12544.f, B*64*49);
  // [11] conv4 (64->2, 7x7) naive (tiny)
  conv3x3_kernel<<<nb((long long)B*2*49), 256, 0, stream>>>(a41, conv4_w, conv4_b, a4,
                                                            B, 64, 2, 7, 7, 2, 0, 0);
  // [12] convT4m: 2->128, s=2, p=1, 7->13, parity-decomposed
  convt_s2_tiled<7,7,2,128,false><<<dim3(B,8), 256, 0, stream>>>(a4, conv4m_w, conv4m_b, t4m);
  // [13] convT3m: 128->64, s=1 == conv pad2 flipped, 32-o tile, +elu
  conv_tiled_w2<13,13,15,15,2,true><<<dim3(B,2), 256, 0, stream>>>(t4m, conv3m_w, conv3m_b, t3m,
                                                                   nullptr, nullptr, 128, 64, 64, 2);
  // [14] convT2m: 64->32, s=2, p=1, 15->29, +elu, parity-decomposed
  convt_s2_tiled<15,15,64,32,true><<<dim3(B,2), 256, 0, stream>>>(t3m, conv2m_w, conv2m_b, t2m);
  // [15] convT1m: 32->2, k=2, s=1, p=1, 29->28, +elu (naive, tiny)
  convt_kernel<<<nb((long long)B*2*784), 256, 0, stream>>>(t2m, conv1m_w, conv1m_b, t1m,
                                                           B, 32, 2, 29, 29, 28, 28, 2, 1, 0, 1);
  // [16] final warp
  warp_kernel<<<nb((long long)B*784), 256, 0, stream>>>(t1m, x1, (float*)d_out, B);
}

// Round 9
// 1684.659 us; speedup vs baseline: 5.0199x; 1.0694x over previous
//
#include <hip/hip_runtime.h>
#include <hip/hip_bf16.h>

__device__ __forceinline__ float eluf(float x){ return x > 0.f ? x : expm1f(x); }

// ---------------- naive 3x3 pad-1 conv (kept only for tiny conv4) ----------------
__global__ void conv3x3_kernel(const float* __restrict__ in, const float* __restrict__ w,
                               const float* __restrict__ bias, float* __restrict__ out,
                               int B, int Cin, int Cout, int H, int W, int Ctot, int ooff, int act)
{
  int idx = blockIdx.x*256 + threadIdx.x;
  int total = B*Cout*H*W;
  if (idx >= total) return;
  int x = idx % W; int t = idx / W;
  int y = t % H;   t /= H;
  int o = t % Cout; int b = t / Cout;
  float acc = bias ? bias[o] : 0.f;
  const float* wp = w + (long long)o*Cin*9;
  for (int c = 0; c < Cin; c++){
    const float* ip = in + (long long)(b*Cin + c)*H*W;
    const float* wc = wp + c*9;
    #pragma unroll
    for (int ky = 0; ky < 3; ky++){
      int iy = y + ky - 1; if ((unsigned)iy >= (unsigned)H) continue;
      #pragma unroll
      for (int kx = 0; kx < 3; kx++){
        int ix = x + kx - 1; if ((unsigned)ix >= (unsigned)W) continue;
        acc += wc[ky*3+kx] * ip[iy*W + ix];
      }
    }
  }
  if (act == 1) acc = 1.f/(1.f + expf(-acc));
  out[(((long long)b*Ctot + ooff + o)*H + y)*W + x] = acc;
}

// ---------------- conv1: 2->64, 28x28, fused bn-stats ----------------
__global__ __launch_bounds__(256)
void conv1_tiled(const float* __restrict__ in, const float* __restrict__ w,
                 const float* __restrict__ bias, float* __restrict__ out,
                 float* __restrict__ sum, float* __restrict__ sq)
{
  __shared__ float img[2][30*31];
  __shared__ float wl[2][8*9];
  const int b = blockIdx.x, o0 = blockIdx.y*8, t = threadIdx.x;
  const int ol = t >> 5, y = t & 31;
  for (int idx = t; idx < 2*930; idx += 256) ((float*)img)[idx] = 0.f;
  __syncthreads();
  for (int idx = t; idx < 2*784; idx += 256){
    int cl = idx/784, r = idx%784;
    img[cl][(r/28 + 1)*31 + (r%28) + 1] = in[((long long)b*2)*784 + idx];
  }
  if (t < 144){
    int cl = t/72, r = t%72;
    wl[cl][r] = w[(((long long)(o0 + r/9))*2 + cl)*9 + (r%9)];
  }
  __syncthreads();
  const bool active = (y < 28);
  float acc[28];
  #pragma unroll
  for (int x = 0; x < 28; x++) acc[x] = 0.f;
  if (active){
    for (int cl = 0; cl < 2; cl++){
      #pragma unroll
      for (int ky = 0; ky < 3; ky++){
        const float* row = &img[cl][(y+ky)*31];
        float rin[30];
        #pragma unroll
        for (int x = 0; x < 30; x++) rin[x] = row[x];
        #pragma unroll
        for (int kx = 0; kx < 3; kx++){
          float wv = wl[cl][ol*9 + ky*3 + kx];
          #pragma unroll
          for (int x = 0; x < 28; x++) acc[x] += wv * rin[x+kx];
        }
      }
    }
  }
  const int og = o0 + ol;
  float sv = 0.f, qv = 0.f;
  if (active){
    float bv = bias[og];
    float* po = out + (((long long)b*64 + og)*28 + y)*28;
    #pragma unroll
    for (int x = 0; x < 28; x++){
      float v = acc[x] + bv;
      po[x] = v;
      sv += v; qv += v*v;
    }
  }
  #pragma unroll
  for (int d = 16; d > 0; d >>= 1){
    sv += __shfl_down(sv, d, 32);
    qv += __shfl_down(qv, d, 32);
  }
  if (y == 0){ atomicAdd(&sum[og], sv); atomicAdd(&sq[og], qv); }
}

// ---------------- tiled 3x3 conv, CS=1, 16-o tile (for small Cout convs) ----------------
template<int HIN,int WIN,int HOUT,int WOUT,int PAD>
__global__ __launch_bounds__(256)
void conv_tiled(const float* __restrict__ in, const float* __restrict__ w,
                const float* __restrict__ bias, float* __restrict__ out,
                int Cin, int Cout, int Ctot, int ooff, int act)
{
  constexpr int HP = HIN + 2*PAD, WP = WIN + 2*PAD, WPL = WP + 1;
  __shared__ float img[HP*WPL];
  __shared__ float wl[16*9];
  const int b  = blockIdx.x;
  const int o0 = blockIdx.y * 16;
  const int t  = threadIdx.x;
  const int ol = t >> 4, y = t & 15;
  const bool act_th = (y < HOUT) && (o0 + ol < Cout);
  float acc[WOUT];
  #pragma unroll
  for (int x = 0; x < WOUT; x++) acc[x] = 0.f;
  for (int idx = t; idx < HP*WPL; idx += 256) img[idx] = 0.f;
  const long long inb = (long long)b*Cin*HIN*WIN;
  for (int c = 0; c < Cin; c++){
    __syncthreads();
    for (int idx = t; idx < HIN*WIN; idx += 256){
      int iy = idx / WIN, ix = idx % WIN;
      img[(iy+PAD)*WPL + (ix+PAD)] = in[inb + (long long)c*HIN*WIN + idx];
    }
    if (t < 144){
      int oo = t / 9, kk = t % 9;
      int og = o0 + oo;
      wl[t] = (og < Cout) ? w[((long long)og*Cin + c)*9 + kk] : 0.f;
    }
    __syncthreads();
    if (act_th){
      #pragma unroll
      for (int ky = 0; ky < 3; ky++){
        const float* row = &img[(y+ky)*WPL];
        float rin[WOUT+2];
        #pragma unroll
        for (int x = 0; x < WOUT+2; x++) rin[x] = row[x];
        #pragma unroll
        for (int kx = 0; kx < 3; kx++){
          float wv = wl[ol*9 + ky*3 + kx];
          #pragma unroll
          for (int x = 0; x < WOUT; x++) acc[x] += wv * rin[x+kx];
        }
      }
    }
  }
  if (act_th){
    int og = o0 + ol;
    float bv = bias[og];
    #pragma unroll
    for (int x = 0; x < WOUT; x++){
      float v = acc[x] + bv;
      if (act == 1) v = 1.f/(1.f + expf(-v));
      else if (act == 2) v = eluf(v);
      out[(((long long)b*Ctot + ooff + og)*HOUT + y)*WOUT + x] = v;
    }
  }
}

// ---------------- tiled 3x3 conv, CS=1, 32-o tile (2 o's per thread) ----------------
template<int HIN,int WIN,int HOUT,int WOUT,int PAD,bool TRANSP>
__global__ __launch_bounds__(256)
void conv_tiled_w2(const float* __restrict__ in, const float* __restrict__ w,
                   const float* __restrict__ bias, float* __restrict__ out,
                   float* __restrict__ sum, float* __restrict__ sq,
                   int Cin, int Cout, int CoutW, int act)
{
  constexpr int HP = HIN + 2*PAD, WP = WIN + 2*PAD, WPL = WP + 1;
  __shared__ float img[HP*WPL];
  __shared__ float wl[32*9];
  const int b  = blockIdx.x;
  const int o0 = blockIdx.y * 32;
  const int t  = threadIdx.x;
  const int ol = t >> 4, y = t & 15;
  const bool act_th = (y < HOUT);
  float acc0[WOUT], acc1[WOUT];
  #pragma unroll
  for (int x = 0; x < WOUT; x++){ acc0[x] = 0.f; acc1[x] = 0.f; }
  for (int idx = t; idx < HP*WPL; idx += 256) img[idx] = 0.f;
  const long long inb = (long long)b*Cin*HIN*WIN;
  for (int c = 0; c < Cin; c++){
    __syncthreads();
    for (int idx = t; idx < HIN*WIN; idx += 256){
      int iy = idx / WIN, ix = idx % WIN;
      img[(iy+PAD)*WPL + (ix+PAD)] = in[inb + (long long)c*HIN*WIN + idx];
    }
    for (int idx = t; idx < 288; idx += 256){
      int oo = idx / 9, kk = idx % 9;
      int og = o0 + oo;
      float wv;
      if (TRANSP) wv = w[((long long)c*CoutW + og)*9 + (2 - kk/3)*3 + (2 - kk%3)];
      else        wv = w[((long long)og*Cin + c)*9 + kk];
      wl[idx] = wv;
    }
    __syncthreads();
    if (act_th){
      #pragma unroll
      for (int ky = 0; ky < 3; ky++){
        const float* row = &img[(y+ky)*WPL];
        float rin[WOUT+2];
        #pragma unroll
        for (int x = 0; x < WOUT+2; x++) rin[x] = row[x];
        #pragma unroll
        for (int kx = 0; kx < 3; kx++){
          float wv0 = wl[ol*9 + ky*3 + kx];
          float wv1 = wl[(ol+16)*9 + ky*3 + kx];
          #pragma unroll
          for (int x = 0; x < WOUT; x++){
            acc0[x] += wv0 * rin[x+kx];
            acc1[x] += wv1 * rin[x+kx];
          }
        }
      }
    }
  }
  const int og0 = o0 + ol, og1 = o0 + ol + 16;
  float sv0 = 0.f, qv0 = 0.f, sv1 = 0.f, qv1 = 0.f;
  if (act_th){
    float bv0 = bias[og0], bv1 = bias[og1];
    float* po0 = out + (((long long)b*Cout + og0)*HOUT + y)*WOUT;
    float* po1 = out + (((long long)b*Cout + og1)*HOUT + y)*WOUT;
    #pragma unroll
    for (int x = 0; x < WOUT; x++){
      float v0 = acc0[x] + bv0;
      float v1 = acc1[x] + bv1;
      po0[x] = (act == 2) ? eluf(v0) : v0;
      po1[x] = (act == 2) ? eluf(v1) : v1;
      sv0 += v0; qv0 += v0*v0; sv1 += v1; qv1 += v1*v1;
    }
  }
  if (sum){
    #pragma unroll
    for (int d = 8; d > 0; d >>= 1){
      sv0 += __shfl_down(sv0, d, 16); qv0 += __shfl_down(qv0, d, 16);
      sv1 += __shfl_down(sv1, d, 16); qv1 += __shfl_down(qv1, d, 16);
    }
    if (y == 0){
      atomicAdd(&sum[og0], sv0); atomicAdd(&sq[og0], qv0);
      atomicAdd(&sum[og1], sv1); atomicAdd(&sq[og1], qv1);
    }
  }
}

// ---------------- stride-2 transpose conv, parity-decomposed ----------------
template<int HIN,int WIN,int CIN,int COUT,bool DO_ELU>
__global__ __launch_bounds__(256)
void convt_s2_tiled(const float* __restrict__ in, const float* __restrict__ w,
                    const float* __restrict__ bias, float* __restrict__ out)
{
  constexpr int HOUT = 2*HIN - 1, WOUT = 2*WIN - 1;
  __shared__ float img[17*16];
  __shared__ float wl[16][10];
  const int b  = blockIdx.x;
  const int o0 = blockIdx.y * 16;
  const int t  = threadIdx.x;
  const int ol = t >> 4, yb = t & 15;
  for (int idx = t; idx < 17*16; idx += 256) img[idx] = 0.f;
  float accA[WOUT], accB[WOUT];
  #pragma unroll
  for (int x = 0; x < WOUT; x++){ accA[x] = 0.f; accB[x] = 0.f; }
  for (int c = 0; c < CIN; c++){
    __syncthreads();
    for (int idx = t; idx < HIN*WIN; idx += 256)
      img[(idx/WIN)*16 + idx%WIN] = in[((long long)b*CIN + c)*HIN*WIN + idx];
    if (t < 144)
      wl[t/9][t%9] = w[(((long long)c*COUT + o0 + t/9)*3 + (t%9)/3)*3 + (t%9)%3];
    __syncthreads();
    float ru[16], rd[16];
    #pragma unroll
    for (int q = 0; q < 4; q++){
      float4 va = ((const float4*)&img[yb*16])[q];
      ru[4*q+0]=va.x; ru[4*q+1]=va.y; ru[4*q+2]=va.z; ru[4*q+3]=va.w;
      float4 vb = ((const float4*)&img[(yb+1)*16])[q];
      rd[4*q+0]=vb.x; rd[4*q+1]=vb.y; rd[4*q+2]=vb.z; rd[4*q+3]=vb.w;
    }
    float w00=wl[ol][0], w01=wl[ol][1], w02=wl[ol][2];
    float w10=wl[ol][3], w11=wl[ol][4], w12=wl[ol][5];
    float w20=wl[ol][6], w21=wl[ol][7], w22=wl[ol][8];
    #pragma unroll
    for (int v = 0; v < WIN; v++){
      accA[2*v] += w11*ru[v];
      accB[2*v] += w21*ru[v] + w01*rd[v];
    }
    #pragma unroll
    for (int v = 0; v < WIN-1; v++){
      accA[2*v+1] += w12*ru[v] + w10*ru[v+1];
      accB[2*v+1] += w22*ru[v] + w20*ru[v+1] + w02*rd[v] + w00*rd[v+1];
    }
  }
  const int og = o0 + ol;
  const float bv = bias[og];
  const int yA = 2*yb, yB = 2*yb + 1;
  if (yA < HOUT){
    float* po = out + (((long long)b*COUT + og)*HOUT + yA)*WOUT;
    #pragma unroll
    for (int x = 0; x < WOUT; x++){ float v = accA[x] + bv; po[x] = DO_ELU ? eluf(v) : v; }
  }
  if (yB < HOUT){
    float* po = out + (((long long)b*COUT + og)*HOUT + yB)*WOUT;
    #pragma unroll
    for (int x = 0; x < WOUT; x++){ float v = accB[x] + bv; po[x] = DO_ELU ? eluf(v) : v; }
  }
}

// ---------------- deform weight transpose: w[o][c][kk] -> wT[cc][cl*9+kk][o] ----------------
__global__ void wtrans_kernel(const float* __restrict__ w, float* __restrict__ wT,
                              int CIN, int COUT)
{
  int n = CIN*COUT*9;
  int idx = blockIdx.x*256 + threadIdx.x;
  if (idx >= n) return;
  int cc = idx / (72*COUT);
  int r  = idx % (72*COUT);
  int k  = r / COUT, o = r % COUT;
  int c  = cc*8 + k/9, kk = k%9;
  wT[idx] = w[((long long)o*CIN + c)*9 + kk];
}

// ---------------- deformable conv: gather + register-tiled GEMM ----------------
// thread tile: 4 o's (og = t%OG) x PT px (pxg = t/OG). PXTP=64, S padded/zeroed.
template<int CIN,int COUT,int H,int W,int PXT,int OG,int PG>
__global__ __launch_bounds__(256)
void deform_gemm(const float* __restrict__ x, const float* __restrict__ om,
                 const float* __restrict__ wT, float* __restrict__ out,
                 float* __restrict__ sum, float* __restrict__ sq)
{
  constexpr int HW = H*W;
  constexpr int NT = (HW + PXT - 1)/PXT;
  constexpr int PXTP = 64;
  constexpr int OT = COUT/OG;      // 4
  constexpr int PT = PXTP/PG;      // 8 (dc2) or 4 (dc41)
  __shared__ __align__(16) float simg[8*HW];
  __shared__ __align__(16) float S[72*PXTP];
  __shared__ float kwv[PXT*9*4];
  __shared__ int   kidx[PXT*9*4];
  __shared__ float sred[COUT], qred[COUT];
  const int tile = blockIdx.x % NT;
  const int b    = blockIdx.x / NT;
  const int t    = threadIdx.x;
  const int og   = t % OG;
  const int pxg  = t / OG;
  const int Hp = H + 2, Wp = W + 2;
  if (t < COUT){ sred[t] = 0.f; qred[t] = 0.f; }
  // phase 0: bilinear corner weights/indices per (px, kk), mask folded in
  for (int it = t; it < PXT*9; it += 256){
    int px = it / 9, kk = it % 9;
    int p = tile*PXT + px;
    float w0=0.f,w1=0.f,w2=0.f,w3=0.f;
    int i0=0,i1=0,i2=0,i3=0;
    if (p < HW){
      int i = p / W, j = p % W;
      long long base = ((long long)b*27)*HW + p;
      float offx = om[base + (long long)kk*HW];
      float offy = om[base + (long long)(9+kk)*HW];
      float mk   = om[base + (long long)(18+kk)*HW];
      float pnx = (float)(kk/3) - 1.f;
      float pny = (float)(kk%3) - 1.f;
      float px_ = fminf(fmaxf((float)(i+1) + pnx + offx, 0.f), (float)(Hp-1));
      float py_ = fminf(fmaxf((float)(j+1) + pny + offy, 0.f), (float)(Wp-1));
      float fx = floorf(px_), fy = floorf(py_);
      float x0 = fmaxf(fx, 0.f), y0 = fmaxf(fy, 0.f);
      float x1c = fminf(fx + 1.f, (float)(Hp-1));
      float y1c = fminf(fy + 1.f, (float)(Wp-1));
      float glt = (1.f + (x0 - px_)) * (1.f + (y0 - py_));
      float grb = (1.f - (x1c - px_)) * (1.f - (y1c - py_));
      float glb = (1.f + (x0 - px_)) * (1.f - (y1c - py_));
      float grt = (1.f - (x1c - px_)) * (1.f + (y0 - py_));
      int ax0=(int)x0, ay0=(int)y0, ax1=(int)x1c, ay1=(int)y1c;
      if (ax0>=1 && ax0<=H && ay0>=1 && ay0<=W){ w0 = glt*mk; i0 = (ax0-1)*W + (ay0-1); }
      if (ax1>=1 && ax1<=H && ay1>=1 && ay1<=W){ w1 = grb*mk; i1 = (ax1-1)*W + (ay1-1); }
      if (ax0>=1 && ax0<=H && ay1>=1 && ay1<=W){ w2 = glb*mk; i2 = (ax0-1)*W + (ay1-1); }
      if (ax1>=1 && ax1<=H && ay0>=1 && ay0<=W){ w3 = grt*mk; i3 = (ax1-1)*W + (ay0-1); }
    }
    int b4 = it*4;
    kwv[b4+0]=w0; kwv[b4+1]=w1; kwv[b4+2]=w2; kwv[b4+3]=w3;
    kidx[b4+0]=i0; kidx[b4+1]=i1; kidx[b4+2]=i2; kidx[b4+3]=i3;
  }
  float acc[OT][PT];
  #pragma unroll
  for (int oi = 0; oi < OT; oi++)
    #pragma unroll
    for (int pp = 0; pp < PT; pp++) acc[oi][pp] = 0.f;
  for (int cc = 0; cc < CIN/8; cc++){
    __syncthreads();
    for (int idx = t; idx < 8*HW; idx += 256)
      simg[idx] = x[((long long)b*CIN + cc*8)*HW + idx];
    __syncthreads();
    // build S[k][px], zero pads
    for (int idx = t; idx < 72*PXTP; idx += 256){
      int k = idx >> 6, px = idx & 63;
      float v = 0.f;
      if (px < PXT){
        int b4 = (px*9 + (k%9))*4;
        const float* im = &simg[(k/9)*HW];
        v = kwv[b4+0]*im[kidx[b4+0]] + kwv[b4+1]*im[kidx[b4+1]]
          + kwv[b4+2]*im[kidx[b4+2]] + kwv[b4+3]*im[kidx[b4+3]];
      }
      S[idx] = v;
    }
    __syncthreads();
    const float* wc = wT + (long long)cc*72*COUT;
    #pragma unroll 2
    for (int k = 0; k < 72; k++){
      const float4 wv = *(const float4*)(wc + k*COUT + og*4);
      #pragma unroll
      for (int pq = 0; pq < PT/4; pq++){
        const float4 s4 = *(const float4*)(&S[k*PXTP + pxg*PT + pq*4]);
        acc[0][pq*4+0] += wv.x*s4.x; acc[0][pq*4+1] += wv.x*s4.y;
        acc[0][pq*4+2] += wv.x*s4.z; acc[0][pq*4+3] += wv.x*s4.w;
        acc[1][pq*4+0] += wv.y*s4.x; acc[1][pq*4+1] += wv.y*s4.y;
        acc[1][pq*4+2] += wv.y*s4.z; acc[1][pq*4+3] += wv.y*s4.w;
        acc[2][pq*4+0] += wv.z*s4.x; acc[2][pq*4+1] += wv.z*s4.y;
        acc[2][pq*4+2] += wv.z*s4.z; acc[2][pq*4+3] += wv.z*s4.w;
        acc[3][pq*4+0] += wv.w*s4.x; acc[3][pq*4+1] += wv.w*s4.y;
        acc[3][pq*4+2] += wv.w*s4.z; acc[3][pq*4+3] += wv.w*s4.w;
      }
    }
  }
  // epilogue: store + per-o stats
  float svl[OT], qvl[OT];
  #pragma unroll
  for (int oi = 0; oi < OT; oi++){ svl[oi] = 0.f; qvl[oi] = 0.f; }
  #pragma unroll
  for (int oi = 0; oi < OT; oi++){
    int o = og*OT + oi;
    #pragma unroll
    for (int pp = 0; pp < PT; pp++){
      int pxl = pxg*PT + pp;
      if (pxl < PXT){
        int p = tile*PXT + pxl;
        if (p < HW){
          float v = acc[oi][pp];
          out[((long long)b*COUT + o)*HW + p] = v;
          svl[oi] += v; qvl[oi] += v*v;
        }
      }
    }
  }
  #pragma unroll
  for (int oi = 0; oi < OT; oi++){
    atomicAdd(&sred[og*OT + oi], svl[oi]);
    atomicAdd(&qred[og*OT + oi], qvl[oi]);
  }
  __syncthreads();
  if (t < COUT){ atomicAdd(&sum[t], sred[t]); atomicAdd(&sq[t], qred[t]); }
}

// ---------------- bn + elu + 2x2 avgpool ----------------
__global__ void bn_elu_pool_kernel(const float* __restrict__ in, const float* __restrict__ g,
                                   const float* __restrict__ bb, const float* __restrict__ sum,
                                   const float* __restrict__ sq, float* __restrict__ out,
                                   int B, int C, int H, int W, float invN)
{
  int Ho = H/2, Wo = W/2;
  int idx = blockIdx.x*256 + threadIdx.x;
  int total = B*C*Ho*Wo;
  if (idx >= total) return;
  int x = idx % Wo; int t = idx / Wo;
  int y = t % Ho;   t /= Ho;
  int c = t % C;    int b = t / C;
  float mean = sum[c]*invN;
  float var  = sq[c]*invN - mean*mean;
  float sc = g[c] * rsqrtf(var + 1e-5f);
  float sh = bb[c] - mean*sc;
  const float* p = in + (long long)(b*C + c)*H*W;
  float acc = 0.f;
  #pragma unroll
  for (int dy = 0; dy < 2; dy++)
    #pragma unroll
    for (int dx = 0; dx < 2; dx++)
      acc += eluf(sc*p[(2*y+dy)*W + (2*x+dx)] + sh);
  out[idx] = acc * 0.25f;
}

// ---------------- bn + elu in place ----------------
__global__ void bn_elu_inplace_kernel(float* __restrict__ xio, const float* __restrict__ g,
                                      const float* __restrict__ bb, const float* __restrict__ sum,
                                      const float* __restrict__ sq, int C, int HW, float invN, int total)
{
  int idx = blockIdx.x*256 + threadIdx.x;
  if (idx >= total) return;
  int c = (idx / HW) % C;
  float mean = sum[c]*invN;
  float var  = sq[c]*invN - mean*mean;
  float sc = g[c] * rsqrtf(var + 1e-5f);
  float sh = bb[c] - mean*sc;
  xio[idx] = eluf(sc*xio[idx] + sh);
}

// ---------------- generic transpose conv (kept for convT1m) ----------------
__global__ void convt_kernel(const float* __restrict__ in, const float* __restrict__ w,
                             const float* __restrict__ bias, float* __restrict__ out,
                             int B, int Cin, int Cout, int Hin, int Win, int Hout, int Wout,
                             int K, int S, int PP, int do_elu)
{
  int idx = blockIdx.x*256 + threadIdx.x;
  int total = B*Cout*Hout*Wout;
  if (idx >= total) return;
  int x = idx % Wout; int t = idx / Wout;
  int y = t % Hout;   t /= Hout;
  int o = t % Cout;   int b = t / Cout;
  float acc = bias[o];
  for (int ky = 0; ky < K; ky++){
    int dy = y + ky - PP;
    if (dy < 0 || (dy % S) != 0) continue;
    int iy = dy / S; if (iy >= Hin) continue;
    int wky = K - 1 - ky;
    for (int kx = 0; kx < K; kx++){
      int dx = x + kx - PP;
      if (dx < 0 || (dx % S) != 0) continue;
      int ix = dx / S; if (ix >= Win) continue;
      int wkx = K - 1 - kx;
      const float* ip = in + (long long)b*Cin*Hin*Win + (long long)iy*Win + ix;
      for (int c = 0; c < Cin; c++){
        acc += w[(((long long)c*Cout + o)*K + wky)*K + wkx] * ip[(long long)c*Hin*Win];
      }
    }
  }
  if (do_elu) acc = eluf(acc);
  out[idx] = acc;
}

// ---------------- final bicubic warp ----------------
__device__ __forceinline__ float cubicf(float A, float Bv, float C, float D, float t){
  float a = -0.5f*A + 1.5f*Bv - 1.5f*C + 0.5f*D;
  float b =  A - 2.5f*Bv + 2.0f*C - 0.5f*D;
  float c = -0.5f*A + 0.5f*C;
  return ((a*t + b)*t + c)*t + Bv;
}

__global__ void warp_kernel(const float* __restrict__ V, const float* __restrict__ x1,
                            float* __restrict__ out, int B)
{
  int idx = blockIdx.x*256 + threadIdx.x;
  int total = B*784;
  if (idx >= total) return;
  int j = idx % 28; int t = idx / 28;
  int i = t % 28;   int b = t / 28;
  float v0 = V[((long long)b*2 + 0)*784 + j*28 + i];
  float v1 = V[((long long)b*2 + 1)*784 + j*28 + i];
  float gx = (-1.f + 2.f*(float)j/27.f) + v0;
  float gy = (-1.f + 2.f*(float)i/27.f) + v1;
  float ix = (gx + 1.f)*13.5f;
  float iy = (gy + 1.f)*13.5f;
  float x0 = floorf(ix), y0 = floorf(iy);
  float tx = ix - x0, ty = iy - y0;
  const float* img = x1 + (long long)b*2*784;
  float rows[4];
  #pragma unroll
  for (int ky = -1; ky <= 2; ky++){
    int yi = (int)fminf(fmaxf(y0 + (float)ky, 0.f), 27.f);
    float cv[4];
    #pragma unroll
    for (int kx = -1; kx <= 2; kx++){
      int xi = (int)fminf(fmaxf(x0 + (float)kx, 0.f), 27.f);
      cv[kx+1] = img[yi*28 + xi];
    }
    rows[ky+1] = cubicf(cv[0], cv[1], cv[2], cv[3], tx);
  }
  out[idx] = cubicf(rows[0], rows[1], rows[2], rows[3], ty);
}

// ---------------- host ----------------
extern "C" void kernel_launch(void* const* d_in, const int* in_sizes, int n_in,
                              void* d_out, int out_size, void* d_ws, size_t ws_size,
                              hipStream_t stream)
{
  const int B = 256;
  const float* x1      = (const float*)d_in[0];
  const float* conv1_w = (const float*)d_in[9];
  const float* conv1_b = (const float*)d_in[10];
  const float* bn1_g   = (const float*)d_in[11];
  const float* bn1_b   = (const float*)d_in[12];
  const float* dc2_pw  = (const float*)d_in[13];
  const float* dc2_pb  = (const float*)d_in[14];
  const float* dc2_mw  = (const float*)d_in[15];
  const float* dc2_mb  = (const float*)d_in[16];
  const float* dc2_w   = (const float*)d_in[17];
  const float* bn2_g   = (const float*)d_in[18];
  const float* bn2_b   = (const float*)d_in[19];
  const float* conv3_w = (const float*)d_in[20];
  const float* conv3_b = (const float*)d_in[21];
  const float* bn3_g   = (const float*)d_in[22];
  const float* bn3_b   = (const float*)d_in[23];
  const float* dc41_pw = (const float*)d_in[24];
  const float* dc41_pb = (const float*)d_in[25];
  const float* dc41_mw = (const float*)d_in[26];
  const float* dc41_mb = (const float*)d_in[27];
  const float* dc41_w  = (const float*)d_in[28];
  const float* bn41_g  = (const float*)d_in[29];
  const float* bn41_b  = (const float*)d_in[30];
  const float* conv4_w = (const float*)d_in[31];
  const float* conv4_b = (const float*)d_in[32];
  const float* conv4m_w= (const float*)d_in[33];
  const float* conv4m_b= (const float*)d_in[34];
  const float* conv3m_w= (const float*)d_in[35];
  const float* conv3m_b= (const float*)d_in[36];
  const float* conv2m_w= (const float*)d_in[37];
  const float* conv2m_b= (const float*)d_in[38];
  const float* conv1m_w= (const float*)d_in[39];
  const float* conv1m_b= (const float*)d_in[40];

  float* ws = (float*)d_ws;

  // lifetime-packed arena (floats), stats in [0,1024). (layout identical to R7/R8 — verified)
  const long long AB = 1024;
  float* p1   = ws + AB;
  float* a1   = ws + AB + 3211264;
  float* om2  = ws + AB + 3211264;
  float* a2   = ws + AB + 4566016;
  float* a3   = ws + AB + 10988544;
  float* p2   = ws + AB;
  float* om41 = ws + AB + 1605632;
  float* a41  = ws + AB + 1944320;
  float* a4   = ws + AB + 2747136;
  float* t4m  = ws + AB + 2772224;
  float* t3m  = ws + AB + 8310016;
  float* t2m  = ws + AB + 11996416;
  float* t1m  = ws + AB;
  float* wT2  = ws + AB + 17411072;
  float* wT41 = ws + AB + 17484800;

  float* s1  = ws + 0;   float* q1  = ws + 64;
  float* s2  = ws + 128; float* q2  = ws + 256;
  float* s3  = ws + 384; float* q3  = ws + 512;
  float* s41 = ws + 640; float* q41 = ws + 704;

  auto nb = [](long long n){ return (int)((n + 255)/256); };

  hipMemsetAsync(d_ws, 0, 4096, stream);

  // weight pre-transposes for deform GEMMs
  wtrans_kernel<<<nb(73728), 256, 0, stream>>>(dc2_w,  wT2,  64, 128);
  wtrans_kernel<<<nb(73728), 256, 0, stream>>>(dc41_w, wT41, 128, 64);

  // [1] conv1 (2->64, 28x28), fused bn1 stats
  conv1_tiled<<<dim3(B,8), 256, 0, stream>>>(x1, conv1_w, conv1_b, a1, s1, q1);
  // [2] bn1 + elu + avgpool -> p1
  bn_elu_pool_kernel<<<nb((long long)B*64*196), 256, 0, stream>>>(a1, bn1_g, bn1_b, s1, q1, p1,
                                                                  B, 64, 28, 28, 1.f/200704.f);
  // [3] dc2 offsets (64->18) + mask (64->9, sigmoid) -> om2
  conv_tiled<14,14,14,14,1><<<dim3(B,2), 256, 0, stream>>>(p1, dc2_pw, dc2_pb, om2,
                                                           64, 18, 27, 0, 0);
  conv_tiled<14,14,14,14,1><<<dim3(B,1), 256, 0, stream>>>(p1, dc2_mw, dc2_mb, om2,
                                                           64, 9, 27, 18, 1);
  // [4] deform conv 2 (64->128) -> a2, fused bn2 stats; 4o x 8px register tile
  deform_gemm<64,128,14,14,49,32,8><<<B*4, 256, 0, stream>>>(p1, om2, wT2, a2, s2, q2);
  // [5] bn2 + elu
  bn_elu_inplace_kernel<<<nb((long long)B*128*196), 256, 0, stream>>>(a2, bn2_g, bn2_b, s2, q2,
                                                                      128, 196, 1.f/50176.f, B*128*196);
  // [6] conv3 (128->128) -> a3, 32-o tile, fused bn3 stats
  conv_tiled_w2<14,14,14,14,1,false><<<dim3(B,4), 256, 0, stream>>>(a2, conv3_w, conv3_b, a3,
                                                                    s3, q3, 128, 128, 0, 0);
  // [7] bn3 + elu + avgpool -> p2
  bn_elu_pool_kernel<<<nb((long long)B*128*49), 256, 0, stream>>>(a3, bn3_g, bn3_b, s3, q3, p2,
                                                                  B, 128, 14, 14, 1.f/50176.f);
  // [8] dc41 offsets + mask -> om41
  conv_tiled<7,7,7,7,1><<<dim3(B,2), 256, 0, stream>>>(p2, dc41_pw, dc41_pb, om41,
                                                       128, 18, 27, 0, 0);
  conv_tiled<7,7,7,7,1><<<dim3(B,1), 256, 0, stream>>>(p2, dc41_mw, dc41_mb, om41,
                                                       128, 9, 27, 18, 1);
  // [9] deform conv 41 (128->64) -> a41, fused bn41 stats; 4o x 4px register tile
  deform_gemm<128,64,7,7,49,16,16><<<B*1, 256, 0, stream>>>(p2, om41, wT41, a41, s41, q41);
  // [10] bn41 + elu
  bn_elu_inplace_kernel<<<nb((long long)B*64*49), 256, 0, stream>>>(a41, bn41_g, bn41_b, s41, q41,
                                                                    64, 49, 1.f/12544.f, B*64*49);
  // [11] conv4 (64->2, 7x7) naive (tiny)
  conv3x3_kernel<<<nb((long long)B*2*49), 256, 0, stream>>>(a41, conv4_w, conv4_b, a4,
                                                            B, 64, 2, 7, 7, 2, 0, 0);
  // [12] convT4m: 2->128, s=2, p=1, 7->13, parity-decomposed
  convt_s2_tiled<7,7,2,128,false><<<dim3(B,8), 256, 0, stream>>>(a4, conv4m_w, conv4m_b, t4m);
  // [13] convT3m: 128->64, s=1 == conv pad2 flipped, 32-o tile, +elu
  conv_tiled_w2<13,13,15,15,2,true><<<dim3(B,2), 256, 0, stream>>>(t4m, conv3m_w, conv3m_b, t3m,
                                                                   nullptr, nullptr, 128, 64, 64, 2);
  // [14] convT2m: 64->32, s=2, p=1, 15->29, +elu, parity-decomposed
  convt_s2_tiled<15,15,64,32,true><<<dim3(B,2), 256, 0, stream>>>(t3m, conv2m_w, conv2m_b, t2m);
  // [15] convT1m: 32->2, k=2, s=1, p=1, 29->28, +elu (naive, tiny)
  convt_kernel<<<nb((long long)B*2*784), 256, 0, stream>>>(t2m, conv1m_w, conv1m_b, t1m,
                                                           B, 32, 2, 29, 29, 28, 28, 2, 1, 0, 1);
  // [16] final warp
  warp_kernel<<<nb((long long)B*784), 256, 0, stream>>>(t1m, x1, (float*)d_out, B);
}